// Round 11
// baseline (220.813 us; speedup 1.0000x reference)
//
#include <hip/hip_runtime.h>
#include <math.h>

#define NN 100000
#define NE 1600000
#define NBINS 391          // bin = dst >> 8
#define CVT_B 6250         // blocks for cvt section of prep
// IN = HID = 64, OUT = 40

typedef unsigned long long ull;
typedef float f32x4 __attribute__((ext_vector_type(4)));
typedef short s16x8 __attribute__((ext_vector_type(8)));

__device__ __forceinline__ unsigned short f2bf(float f) {
    unsigned b = __float_as_uint(f);
    return (unsigned short)((b + 0x7fffu + ((b >> 16) & 1u)) >> 16);
}
__device__ __forceinline__ float bf2f(unsigned short s) {
    return __uint_as_float((unsigned)s << 16);
}

// ---------------------------------------------------------------------------
// prep: [0,CVT_B) x->bf16 | [+6) pack W1|root1 | [+5) pack W2|root2 |
//       [rest) dst bin histogram
// ---------------------------------------------------------------------------
__global__ __launch_bounds__(256) void prep_kernel(
        const float* __restrict__ x, unsigned short* __restrict__ xbf,
        const float* __restrict__ W1, const float* __restrict__ root1,
        unsigned short* __restrict__ Bp1,
        const float* __restrict__ W2, const float* __restrict__ root2,
        unsigned short* __restrict__ Bp2,
        const int* __restrict__ dst, int* __restrict__ binCnt) {
    const int b = blockIdx.x;
    const int t = threadIdx.x;
    if (b < CVT_B) {
        const int i = b * 256 + t;
        if (i < NN * 16) {
            const float4 v = ((const float4*)x)[i];
            ushort4 q;
            q.x = f2bf(v.x); q.y = f2bf(v.y); q.z = f2bf(v.z); q.w = f2bf(v.w);
            ((ushort4*)xbf)[i] = q;
        }
    } else if (b < CVT_B + 6) {
        const int gid = (b - CVT_B) * 256 + t;
        if (gid < 6 * 4 * 64) {
            const int kb = gid >> 8;
            const int ct = (gid >> 6) & 3;
            const int l  = gid & 63;
            const int n  = ct * 16 + (l & 15);
            const int k0 = kb * 32 + (l >> 4) * 8;
            #pragma unroll
            for (int j = 0; j < 8; ++j) {
                const int k = k0 + j;
                const float v = (k < 128) ? W1[k * 64 + n] : root1[(k - 128) * 64 + n];
                Bp1[gid * 8 + j] = f2bf(v);
            }
        }
    } else if (b < CVT_B + 11) {
        const int gid = (b - CVT_B - 6) * 256 + t;
        if (gid < 6 * 3 * 64) {
            const int kb = gid / 192;
            const int r  = gid - kb * 192;
            const int ct = r >> 6;
            const int l  = r & 63;
            const int n  = ct * 16 + (l & 15);
            const int k0 = kb * 32 + (l >> 4) * 8;
            #pragma unroll
            for (int j = 0; j < 8; ++j) {
                const int k = k0 + j;
                float v = 0.f;
                if (n < 40) v = (k < 128) ? W2[k * 40 + n] : root2[(k - 128) * 40 + n];
                Bp2[gid * 8 + j] = f2bf(v);
            }
        }
    } else {
        __shared__ int hist[512];
        hist[t] = 0; hist[t + 256] = 0;
        __syncthreads();
        const int hb = b - (CVT_B + 11);
        const int b4 = hb * 2048;
        #pragma unroll
        for (int k = 0; k < 8; ++k) {
            const int i4 = b4 + k * 256 + t;
            if (i4 * 4 < NE) {
                const int4 d4 = ((const int4*)dst)[i4];
                atomicAdd(&hist[d4.x >> 8], 1);
                atomicAdd(&hist[d4.y >> 8], 1);
                atomicAdd(&hist[d4.z >> 8], 1);
                atomicAdd(&hist[d4.w >> 8], 1);
            }
        }
        __syncthreads();
        if (hist[t])       atomicAdd(&binCnt[t],       hist[t]);
        if (hist[t + 256]) atomicAdd(&binCnt[t + 256], hist[t + 256]);
    }
}

// ---------------------------------------------------------------------------
// scan of binCnt[512] -> binStart[513]; binCur = binStart
// ---------------------------------------------------------------------------
__global__ __launch_bounds__(256) void scan_bins_kernel(
        const int* __restrict__ binCnt, int* __restrict__ binStart,
        int* __restrict__ binCur) {
    __shared__ int sa[512], sb[512];
    const int t = threadIdx.x;
    sa[t] = binCnt[t]; sa[t + 256] = binCnt[t + 256];
    __syncthreads();
    int* cur = sa; int* nxt = sb;
    for (int off = 1; off < 512; off <<= 1) {
        for (int j = t; j < 512; j += 256)
            nxt[j] = cur[j] + ((j >= off) ? cur[j - off] : 0);
        __syncthreads();
        int* tmp = cur; cur = nxt; nxt = tmp;
    }
    for (int j = t; j < 512; j += 256) {
        const int ex = (j == 0) ? 0 : cur[j - 1];
        binStart[j] = ex;
        binCur[j]   = ex;
    }
    if (t == 0) binStart[512] = cur[511];
}

// ---------------------------------------------------------------------------
// p3: binned scatter with LDS reorder -> brec grouped by bin.
// brec = [uq:15|dst:17]<<32 | src.
// ---------------------------------------------------------------------------
__global__ __launch_bounds__(256) void p3_bin_scatter_kernel(
        const int* __restrict__ src, const int* __restrict__ dst,
        const float* __restrict__ u, int* __restrict__ binCur,
        ull* __restrict__ brec) {
    __shared__ int cnt[512], lstart[512], gbase[512], lcur[512];
    __shared__ int sa[512], sb[512];
    __shared__ ull buf[2048];
    const int t = threadIdx.x;
    cnt[t] = 0; cnt[t + 256] = 0;
    __syncthreads();
    const int base = blockIdx.x * 2048;
    int mysrc[8], mydst[8];
    float myu[8];
    #pragma unroll
    for (int k = 0; k < 8; ++k) {
        const int i = base + k * 256 + t;
        if (i < NE) {
            mydst[k] = dst[i]; mysrc[k] = src[i]; myu[k] = u[i];
            atomicAdd(&cnt[mydst[k] >> 8], 1);
        } else {
            mydst[k] = -1;
        }
    }
    __syncthreads();
    sa[t] = cnt[t]; sa[t + 256] = cnt[t + 256];
    __syncthreads();
    int* cur = sa; int* nxt = sb;
    for (int off = 1; off < 512; off <<= 1) {
        for (int j = t; j < 512; j += 256)
            nxt[j] = cur[j] + ((j >= off) ? cur[j - off] : 0);
        __syncthreads();
        int* tmp = cur; cur = nxt; nxt = tmp;
    }
    for (int j = t; j < 512; j += 256) {
        const int ex = (j == 0) ? 0 : cur[j - 1];
        lstart[j] = ex;
        lcur[j]   = ex;
    }
    __syncthreads();
    for (int j = t; j < 512; j += 256) {
        const int c = cnt[j];
        gbase[j] = c ? atomicAdd(&binCur[j], c) : 0;
    }
    #pragma unroll
    for (int k = 0; k < 8; ++k) {
        if (mydst[k] >= 0) {
            const int b = mydst[k] >> 8;
            const int lp = atomicAdd(&lcur[b], 1);
            int uq = (int)(myu[k] * 32768.0f + 0.5f);
            if (uq > 32767) uq = 32767;
            const unsigned hi = ((unsigned)uq << 17) | (unsigned)mydst[k];
            buf[lp] = ((ull)hi << 32) | (unsigned)mysrc[k];
        }
    }
    __syncthreads();
    const int total = lstart[511] + cnt[511];
    for (int i = t; i < total; i += 256) {
        const ull r = buf[i];
        const int d = (int)((unsigned)(r >> 32) & 0x1FFFFu);
        const int b = d >> 8;
        brec[(size_t)(gbase[b] + (i - lstart[b]))] = r;
    }
}

// ---------------------------------------------------------------------------
// p4: per-bin finalize: deg + rowstart + CSR scatter (LDS cursors) + global
// degree-class histogram (class = min(deg>>2,63)) for the balance perm.
// ---------------------------------------------------------------------------
__global__ __launch_bounds__(256) void p4_final_kernel(
        const ull* __restrict__ brec, const int* __restrict__ binStart,
        int* __restrict__ deg, int* __restrict__ rowstart,
        unsigned* __restrict__ rec4, int* __restrict__ dcnt) {
    __shared__ int cnt[256], lpos[256], wsum[4], ch[64];
    const int b = blockIdx.x;
    const int s = binStart[b], e = binStart[b + 1];
    const int t = threadIdx.x;
    cnt[t] = 0;
    if (t < 64) ch[t] = 0;
    __syncthreads();
    for (int i = s + t; i < e; i += 256)
        atomicAdd(&cnt[(unsigned)(brec[i] >> 32) & 0xFFu], 1);
    __syncthreads();
    const int lane = t & 63, w = t >> 6;
    const int v = cnt[t];
    int inc = v;
    for (int off = 1; off < 64; off <<= 1) {
        int tv = __shfl_up(inc, off, 64);
        if (lane >= off) inc += tv;
    }
    if (lane == 63) wsum[w] = inc;
    __syncthreads();
    int add = 0;
    #pragma unroll
    for (int i = 0; i < 4; ++i) if (i < w) add += wsum[i];
    const int excl = add + inc - v;
    const int node = b * 256 + t;
    if (node < NN) {
        deg[node]      = v;
        rowstart[node] = s + excl;
        atomicAdd(&ch[(v >> 2) < 63 ? (v >> 2) : 63], 1);
    }
    lpos[t] = s + excl;
    __syncthreads();
    for (int i = s + t; i < e; i += 256) {
        const ull r = brec[i];
        const unsigned hi = (unsigned)(r >> 32);
        const int p = atomicAdd(&lpos[hi & 0xFFu], 1);
        rec4[p] = (hi & 0xFFFE0000u) | (unsigned)(r & 0x1FFFFu);
    }
    __syncthreads();
    if (t < 64 && ch[t]) atomicAdd(&dcnt[t], ch[t]);
}

// ---------------------------------------------------------------------------
// dscan: 64-entry exclusive scan of dcnt -> dcur
// ---------------------------------------------------------------------------
__global__ __launch_bounds__(64) void dscan_kernel(
        const int* __restrict__ dcnt, int* __restrict__ dcur) {
    const int l = threadIdx.x;
    const int v = dcnt[l];
    int inc = v;
    for (int off = 1; off < 64; off <<= 1) {
        int tv = __shfl_up(inc, off, 64);
        if (l >= off) inc += tv;
    }
    dcur[l] = inc - v;
}

// ---------------------------------------------------------------------------
// dplace: counting-sort nodes by degree class -> perm (bijection)
// ---------------------------------------------------------------------------
__global__ __launch_bounds__(256) void dplace_kernel(
        const int* __restrict__ deg, int* __restrict__ dcur,
        int* __restrict__ perm) {
    __shared__ int h[64], basec[64], c2[64];
    const int t = threadIdx.x;
    if (t < 64) h[t] = 0;
    __syncthreads();
    int myc[4], myn[4];
    #pragma unroll
    for (int k = 0; k < 4; ++k) {
        const int n = blockIdx.x * 1024 + k * 256 + t;
        myn[k] = n;
        if (n < NN) {
            const int d = deg[n];
            myc[k] = (d >> 2) < 63 ? (d >> 2) : 63;
            atomicAdd(&h[myc[k]], 1);
        } else myc[k] = -1;
    }
    __syncthreads();
    if (t < 64) {
        basec[t] = h[t] ? atomicAdd(&dcur[t], h[t]) : 0;
        c2[t] = 0;
    }
    __syncthreads();
    #pragma unroll
    for (int k = 0; k < 4; ++k) {
        if (myc[k] >= 0) {
            const int p = basec[myc[k]] + atomicAdd(&c2[myc[k]], 1);
            perm[p] = myn[k];
        }
    }
}

// ---------------------------------------------------------------------------
// agg: CSR gather from bf16 table, degree-balanced via perm, NO LDS.
// 16 threads per node; 8-deep unrolled edge loop.
// ---------------------------------------------------------------------------
__global__ __launch_bounds__(256, 8) void agg_kernel(
        const int* __restrict__ rowstart, const int* __restrict__ deg,
        const int* __restrict__ perm,
        const unsigned* __restrict__ rec4, const unsigned short* __restrict__ featb,
        unsigned short* __restrict__ A) {
    const int t   = blockIdx.x * 256 + threadIdx.x;
    const int grp = t >> 4;
    const int f   = t & 15;
    if (grp >= NN) return;
    const int node = perm[grp];
    const int dg = deg[node];
    const int st = rowstart[node];
    const ushort4* __restrict__ f4 = (const ushort4*)featb;
    const float UQS = 1.0f / 32768.0f;

    float4 sum = make_float4(0.f, 0.f, 0.f, 0.f);
    float4 smu = make_float4(0.f, 0.f, 0.f, 0.f);
    int i = 0;
    for (; i + 8 <= dg; i += 8) {
        #pragma unroll
        for (int jj = 0; jj < 8; ++jj) {
            const unsigned r = rec4[(size_t)(st + i + jj)];
            const float u2 = (float)(r >> 17) * UQS;
            const ushort4 q = f4[(size_t)(r & 0x1FFFFu) * 16 + f];
            const float vx = bf2f(q.x), vy = bf2f(q.y), vz = bf2f(q.z), vw = bf2f(q.w);
            sum.x += vx; sum.y += vy; sum.z += vz; sum.w += vw;
            smu.x = fmaf(u2, vx, smu.x);
            smu.y = fmaf(u2, vy, smu.y);
            smu.z = fmaf(u2, vz, smu.z);
            smu.w = fmaf(u2, vw, smu.w);
        }
    }
    #pragma unroll 4
    for (; i < dg; ++i) {
        const unsigned r = rec4[(size_t)(st + i)];
        const float u2 = (float)(r >> 17) * UQS;
        const ushort4 q = f4[(size_t)(r & 0x1FFFFu) * 16 + f];
        const float vx = bf2f(q.x), vy = bf2f(q.y), vz = bf2f(q.z), vw = bf2f(q.w);
        sum.x += vx; sum.y += vy; sum.z += vz; sum.w += vw;
        smu.x = fmaf(u2, vx, smu.x);
        smu.y = fmaf(u2, vy, smu.y);
        smu.z = fmaf(u2, vz, smu.z);
        smu.w = fmaf(u2, vw, smu.w);
    }
    const float inv = 1.0f / fmaxf((float)dg, 1.0f);
    ushort4 p0, p1;
    p0.x = f2bf((sum.x - smu.x) * inv);
    p0.y = f2bf((sum.y - smu.y) * inv);
    p0.z = f2bf((sum.z - smu.z) * inv);
    p0.w = f2bf((sum.w - smu.w) * inv);
    p1.x = f2bf(smu.x * inv);
    p1.y = f2bf(smu.y * inv);
    p1.z = f2bf(smu.z * inv);
    p1.w = f2bf(smu.w * inv);
    *(ushort4*)&A[(size_t)node * 128 + 4 * f]      = p0;
    *(ushort4*)&A[(size_t)node * 128 + 64 + 4 * f] = p1;
}

// ---------------------------------------------------------------------------
// upd1 (MFMA): hbf = elu([A|x] @ Bp1 + b1)
// ---------------------------------------------------------------------------
__global__ __launch_bounds__(256) void upd1_kernel(
        const unsigned short* __restrict__ A, const unsigned short* __restrict__ xbf,
        const s16x8* __restrict__ Bp, const float* __restrict__ b1,
        unsigned short* __restrict__ hbf) {
    const int tid = threadIdx.x;
    const int w = tid >> 6, l = tid & 63;
    const int kg = l >> 4;
    const int base = blockIdx.x * 64;
    int arow = base + w * 16 + (l & 15);
    if (arow >= NN) arow = NN - 1;
    const s16x8* __restrict__ Ar = (const s16x8*)(A   + (size_t)arow * 128);
    const s16x8* __restrict__ Xr = (const s16x8*)(xbf + (size_t)arow * 64);

    s16x8 af[6];
    #pragma unroll
    for (int kb = 0; kb < 4; ++kb) af[kb] = Ar[kb * 4 + kg];
    af[4] = Xr[kg];
    af[5] = Xr[4 + kg];

    f32x4 acc[4];
    #pragma unroll
    for (int ct = 0; ct < 4; ++ct) acc[ct] = (f32x4){0.f, 0.f, 0.f, 0.f};
    #pragma unroll
    for (int kb = 0; kb < 6; ++kb) {
        #pragma unroll
        for (int ct = 0; ct < 4; ++ct) {
            acc[ct] = __builtin_amdgcn_mfma_f32_16x16x32_bf16(
                af[kb], Bp[(kb * 4 + ct) * 64 + l], acc[ct], 0, 0, 0);
        }
    }

    const int orow0 = base + w * 16 + kg * 4;
    #pragma unroll
    for (int ct = 0; ct < 4; ++ct) {
        const float bv = b1[ct * 16 + (l & 15)];
        #pragma unroll
        for (int j = 0; j < 4; ++j) {
            float v = acc[ct][j] + bv;
            v = (v > 0.f) ? v : (__expf(v) - 1.f);
            const int row = orow0 + j;
            if (row < NN) hbf[(size_t)row * 64 + ct * 16 + (l & 15)] = f2bf(v);
        }
    }
}

// ---------------------------------------------------------------------------
// upd2 (MFMA) + log_softmax: out = lsm([A|h] @ Bp2 + b2), N padded to 48.
// ---------------------------------------------------------------------------
__global__ __launch_bounds__(256) void upd2_kernel(
        const unsigned short* __restrict__ A, const unsigned short* __restrict__ hbf,
        const s16x8* __restrict__ Bp, const float* __restrict__ b2,
        float* __restrict__ out) {
    const int tid = threadIdx.x;
    const int w = tid >> 6, l = tid & 63;
    const int kg = l >> 4;
    const int base = blockIdx.x * 64;
    int arow = base + w * 16 + (l & 15);
    if (arow >= NN) arow = NN - 1;
    const s16x8* __restrict__ Ar = (const s16x8*)(A   + (size_t)arow * 128);
    const s16x8* __restrict__ Xr = (const s16x8*)(hbf + (size_t)arow * 64);

    s16x8 af[6];
    #pragma unroll
    for (int kb = 0; kb < 4; ++kb) af[kb] = Ar[kb * 4 + kg];
    af[4] = Xr[kg];
    af[5] = Xr[4 + kg];

    f32x4 acc[3];
    #pragma unroll
    for (int ct = 0; ct < 3; ++ct) acc[ct] = (f32x4){0.f, 0.f, 0.f, 0.f};
    #pragma unroll
    for (int kb = 0; kb < 6; ++kb) {
        #pragma unroll
        for (int ct = 0; ct < 3; ++ct) {
            acc[ct] = __builtin_amdgcn_mfma_f32_16x16x32_bf16(
                af[kb], Bp[(kb * 3 + ct) * 64 + l], acc[ct], 0, 0, 0);
        }
    }

    const int col = l & 15;
    const float b0 = b2[col], b1v = b2[16 + col];
    const float b2v = (col < 8) ? b2[32 + col] : 0.f;
    #pragma unroll
    for (int j = 0; j < 4; ++j) {
        const float v0 = acc[0][j] + b0;
        const float v1 = acc[1][j] + b1v;
        const float v2 = (col < 8) ? (acc[2][j] + b2v) : -3.0e38f;
        float m = fmaxf(fmaxf(v0, v1), v2);
        #pragma unroll
        for (int off = 1; off < 16; off <<= 1) m = fmaxf(m, __shfl_xor(m, off, 64));
        float s = __expf(v0 - m) + __expf(v1 - m) + ((col < 8) ? __expf(v2 - m) : 0.f);
        #pragma unroll
        for (int off = 1; off < 16; off <<= 1) s += __shfl_xor(s, off, 64);
        const float lse = m + __logf(s);
        const int row = base + w * 16 + kg * 4 + j;
        if (row < NN) {
            float* __restrict__ orow = out + (size_t)row * 40;
            orow[col]      = v0 - lse;
            orow[16 + col] = v1 - lse;
            if (col < 8) orow[32 + col] = v2 - lse;
        }
    }
}

// ---------------------------------------------------------------------------
extern "C" void kernel_launch(void* const* d_in, const int* in_sizes, int n_in,
                              void* d_out, int out_size, void* d_ws, size_t ws_size,
                              hipStream_t stream) {
    const float* x     = (const float*)d_in[0];
    const int*   ei    = (const int*)  d_in[1];
    const float* u     = (const float*)d_in[2];
    const float* W1    = (const float*)d_in[3];
    const float* root1 = (const float*)d_in[4];
    const float* b1    = (const float*)d_in[5];
    const float* W2    = (const float*)d_in[6];
    const float* root2 = (const float*)d_in[7];
    const float* b2    = (const float*)d_in[8];
    float*       out   = (float*)d_out;

    const int* src = ei;
    const int* dst = ei + NE;

    // ws layout
    char* p = (char*)d_ws;
    int* binCnt   = (int*)p;  p += 4 * 512;
    int* dcnt     = (int*)p;  p += 4 * 64;
    int* binStart = (int*)p;  p += 4 * 520;
    int* binCur   = (int*)p;  p += 4 * 512;
    int* dcur     = (int*)p;  p += 4 * 64;
    int* deg      = (int*)p;  p += (size_t)4 * NN;
    int* rowstart = (int*)p;  p += (size_t)4 * NN;
    int* perm     = (int*)p;  p += (size_t)4 * NN;
    ull* brec     = (ull*)p;  p += (size_t)8 * NE;
    unsigned* rec4 = (unsigned*)p;  p += (size_t)4 * NE;
    unsigned short* A   = (unsigned short*)p;  p += (size_t)2 * NN * 128;
    unsigned short* xbf = (unsigned short*)p;  p += (size_t)2 * NN * 64;
    unsigned short* hbf = (unsigned short*)p;  p += (size_t)2 * NN * 64;
    unsigned short* Bp1 = (unsigned short*)p;  p += (size_t)2 * 6 * 4 * 64 * 8;
    unsigned short* Bp2 = (unsigned short*)p;  p += (size_t)2 * 6 * 3 * 64 * 8;

    // zero binCnt + dcnt (contiguous)
    hipMemsetAsync(binCnt, 0, 4 * (512 + 64), stream);

    const int HIST_B = (NE + 8191) / 8192;           // 196
    prep_kernel<<<CVT_B + 11 + HIST_B, 256, 0, stream>>>(
        x, xbf, W1, root1, Bp1, W2, root2, Bp2, dst, binCnt);
    scan_bins_kernel<<<1, 256, 0, stream>>>(binCnt, binStart, binCur);
    p3_bin_scatter_kernel<<<(NE + 2047) / 2048, 256, 0, stream>>>(src, dst, u, binCur, brec);
    p4_final_kernel<<<NBINS, 256, 0, stream>>>(brec, binStart, deg, rowstart, rec4, dcnt);
    dscan_kernel<<<1, 64, 0, stream>>>(dcnt, dcur);
    dplace_kernel<<<(NN + 1023) / 1024, 256, 0, stream>>>(deg, dcur, perm);

    const int AB = (NN * 16 + 255) / 256;
    const int NB = (NN + 63) / 64;
    agg_kernel <<<AB, 256, 0, stream>>>(rowstart, deg, perm, rec4, xbf, A);
    upd1_kernel<<<NB, 256, 0, stream>>>(A, xbf, (const s16x8*)Bp1, b1, hbf);
    agg_kernel <<<AB, 256, 0, stream>>>(rowstart, deg, perm, rec4, hbf, A);
    upd2_kernel<<<NB, 256, 0, stream>>>(A, hbf, (const s16x8*)Bp2, b2, out);
}

// Round 12
// 213.075 us; speedup vs baseline: 1.0363x; 1.0363x over previous
//
#include <hip/hip_runtime.h>
#include <math.h>

#define NN 100000
#define NE 1600000
#define NBINS 391          // bin = dst >> 8
#define CVT_B 6250         // blocks for cvt section of prep
// IN = HID = 64, OUT = 40

typedef unsigned long long ull;
typedef float f32x4 __attribute__((ext_vector_type(4)));
typedef short s16x8 __attribute__((ext_vector_type(8)));

__device__ __forceinline__ unsigned short f2bf(float f) {
    unsigned b = __float_as_uint(f);
    return (unsigned short)((b + 0x7fffu + ((b >> 16) & 1u)) >> 16);
}
__device__ __forceinline__ float bf2f(unsigned short s) {
    return __uint_as_float((unsigned)s << 16);
}

// ---------------------------------------------------------------------------
// prep: [0,CVT_B) x->bf16 | [+6) pack W1|root1 | [+5) pack W2|root2 |
//       [rest) dst bin histogram
// ---------------------------------------------------------------------------
__global__ __launch_bounds__(256) void prep_kernel(
        const float* __restrict__ x, unsigned short* __restrict__ xbf,
        const float* __restrict__ W1, const float* __restrict__ root1,
        unsigned short* __restrict__ Bp1,
        const float* __restrict__ W2, const float* __restrict__ root2,
        unsigned short* __restrict__ Bp2,
        const int* __restrict__ dst, int* __restrict__ binCnt) {
    const int b = blockIdx.x;
    const int t = threadIdx.x;
    if (b < CVT_B) {
        const int i = b * 256 + t;
        if (i < NN * 16) {
            const float4 v = ((const float4*)x)[i];
            ushort4 q;
            q.x = f2bf(v.x); q.y = f2bf(v.y); q.z = f2bf(v.z); q.w = f2bf(v.w);
            ((ushort4*)xbf)[i] = q;
        }
    } else if (b < CVT_B + 6) {
        const int gid = (b - CVT_B) * 256 + t;
        if (gid < 6 * 4 * 64) {
            const int kb = gid >> 8;
            const int ct = (gid >> 6) & 3;
            const int l  = gid & 63;
            const int n  = ct * 16 + (l & 15);
            const int k0 = kb * 32 + (l >> 4) * 8;
            #pragma unroll
            for (int j = 0; j < 8; ++j) {
                const int k = k0 + j;
                const float v = (k < 128) ? W1[k * 64 + n] : root1[(k - 128) * 64 + n];
                Bp1[gid * 8 + j] = f2bf(v);
            }
        }
    } else if (b < CVT_B + 11) {
        const int gid = (b - CVT_B - 6) * 256 + t;
        if (gid < 6 * 3 * 64) {
            const int kb = gid / 192;
            const int r  = gid - kb * 192;
            const int ct = r >> 6;
            const int l  = r & 63;
            const int n  = ct * 16 + (l & 15);
            const int k0 = kb * 32 + (l >> 4) * 8;
            #pragma unroll
            for (int j = 0; j < 8; ++j) {
                const int k = k0 + j;
                float v = 0.f;
                if (n < 40) v = (k < 128) ? W2[k * 40 + n] : root2[(k - 128) * 40 + n];
                Bp2[gid * 8 + j] = f2bf(v);
            }
        }
    } else {
        __shared__ int hist[512];
        hist[t] = 0; hist[t + 256] = 0;
        __syncthreads();
        const int hb = b - (CVT_B + 11);
        const int b4 = hb * 2048;
        #pragma unroll
        for (int k = 0; k < 8; ++k) {
            const int i4 = b4 + k * 256 + t;
            if (i4 * 4 < NE) {
                const int4 d4 = ((const int4*)dst)[i4];
                atomicAdd(&hist[d4.x >> 8], 1);
                atomicAdd(&hist[d4.y >> 8], 1);
                atomicAdd(&hist[d4.z >> 8], 1);
                atomicAdd(&hist[d4.w >> 8], 1);
            }
        }
        __syncthreads();
        if (hist[t])       atomicAdd(&binCnt[t],       hist[t]);
        if (hist[t + 256]) atomicAdd(&binCnt[t + 256], hist[t + 256]);
    }
}

// ---------------------------------------------------------------------------
// scan of binCnt[512] -> binStart[513]; binCur = binStart
// ---------------------------------------------------------------------------
__global__ __launch_bounds__(256) void scan_bins_kernel(
        const int* __restrict__ binCnt, int* __restrict__ binStart,
        int* __restrict__ binCur) {
    __shared__ int sa[512], sb[512];
    const int t = threadIdx.x;
    sa[t] = binCnt[t]; sa[t + 256] = binCnt[t + 256];
    __syncthreads();
    int* cur = sa; int* nxt = sb;
    for (int off = 1; off < 512; off <<= 1) {
        for (int j = t; j < 512; j += 256)
            nxt[j] = cur[j] + ((j >= off) ? cur[j - off] : 0);
        __syncthreads();
        int* tmp = cur; cur = nxt; nxt = tmp;
    }
    for (int j = t; j < 512; j += 256) {
        const int ex = (j == 0) ? 0 : cur[j - 1];
        binStart[j] = ex;
        binCur[j]   = ex;
    }
    if (t == 0) binStart[512] = cur[511];
}

// ---------------------------------------------------------------------------
// p3: binned scatter with LDS reorder -> brec grouped by bin.
// brec = [uq:15|dst:17]<<32 | src.
// ---------------------------------------------------------------------------
__global__ __launch_bounds__(256) void p3_bin_scatter_kernel(
        const int* __restrict__ src, const int* __restrict__ dst,
        const float* __restrict__ u, int* __restrict__ binCur,
        ull* __restrict__ brec) {
    __shared__ int cnt[512], lstart[512], gbase[512], lcur[512];
    __shared__ int sa[512], sb[512];
    __shared__ ull buf[2048];
    const int t = threadIdx.x;
    cnt[t] = 0; cnt[t + 256] = 0;
    __syncthreads();
    const int base = blockIdx.x * 2048;
    int mysrc[8], mydst[8];
    float myu[8];
    #pragma unroll
    for (int k = 0; k < 8; ++k) {
        const int i = base + k * 256 + t;
        if (i < NE) {
            mydst[k] = dst[i]; mysrc[k] = src[i]; myu[k] = u[i];
            atomicAdd(&cnt[mydst[k] >> 8], 1);
        } else {
            mydst[k] = -1;
        }
    }
    __syncthreads();
    sa[t] = cnt[t]; sa[t + 256] = cnt[t + 256];
    __syncthreads();
    int* cur = sa; int* nxt = sb;
    for (int off = 1; off < 512; off <<= 1) {
        for (int j = t; j < 512; j += 256)
            nxt[j] = cur[j] + ((j >= off) ? cur[j - off] : 0);
        __syncthreads();
        int* tmp = cur; cur = nxt; nxt = tmp;
    }
    for (int j = t; j < 512; j += 256) {
        const int ex = (j == 0) ? 0 : cur[j - 1];
        lstart[j] = ex;
        lcur[j]   = ex;
    }
    __syncthreads();
    for (int j = t; j < 512; j += 256) {
        const int c = cnt[j];
        gbase[j] = c ? atomicAdd(&binCur[j], c) : 0;
    }
    #pragma unroll
    for (int k = 0; k < 8; ++k) {
        if (mydst[k] >= 0) {
            const int b = mydst[k] >> 8;
            const int lp = atomicAdd(&lcur[b], 1);
            int uq = (int)(myu[k] * 32768.0f + 0.5f);
            if (uq > 32767) uq = 32767;
            const unsigned hi = ((unsigned)uq << 17) | (unsigned)mydst[k];
            buf[lp] = ((ull)hi << 32) | (unsigned)mysrc[k];
        }
    }
    __syncthreads();
    const int total = lstart[511] + cnt[511];
    for (int i = t; i < total; i += 256) {
        const ull r = buf[i];
        const int d = (int)((unsigned)(r >> 32) & 0x1FFFFu);
        const int b = d >> 8;
        brec[(size_t)(gbase[b] + (i - lstart[b]))] = r;
    }
}

// ---------------------------------------------------------------------------
// p4: per-bin finalize: deg + rowstart + CSR scatter with LDS cursors.
// rec4 = [uq:15]<<17 | src. Bin window L2-local.
// ---------------------------------------------------------------------------
__global__ __launch_bounds__(256) void p4_final_kernel(
        const ull* __restrict__ brec, const int* __restrict__ binStart,
        int* __restrict__ deg, int* __restrict__ rowstart,
        unsigned* __restrict__ rec4) {
    __shared__ int cnt[256], lpos[256], wsum[4];
    const int b = blockIdx.x;
    const int s = binStart[b], e = binStart[b + 1];
    const int t = threadIdx.x;
    cnt[t] = 0;
    __syncthreads();
    for (int i = s + t; i < e; i += 256)
        atomicAdd(&cnt[(unsigned)(brec[i] >> 32) & 0xFFu], 1);
    __syncthreads();
    const int lane = t & 63, w = t >> 6;
    const int v = cnt[t];
    int inc = v;
    for (int off = 1; off < 64; off <<= 1) {
        int tv = __shfl_up(inc, off, 64);
        if (lane >= off) inc += tv;
    }
    if (lane == 63) wsum[w] = inc;
    __syncthreads();
    int add = 0;
    #pragma unroll
    for (int i = 0; i < 4; ++i) if (i < w) add += wsum[i];
    const int excl = add + inc - v;
    const int node = b * 256 + t;
    if (node < NN) {
        deg[node]      = v;
        rowstart[node] = s + excl;
    }
    lpos[t] = s + excl;
    __syncthreads();
    for (int i = s + t; i < e; i += 256) {
        const ull r = brec[i];
        const unsigned hi = (unsigned)(r >> 32);
        const int p = atomicAdd(&lpos[hi & 0xFFu], 1);
        rec4[p] = (hi & 0xFFFE0000u) | (unsigned)(r & 0x1FFFFu);
    }
}

// ---------------------------------------------------------------------------
// fused layer: gather-aggregate (16 lanes x float4 per node, 4 passes) into a
// 16KB XOR-swizzled LDS tile, then MFMA update straight from LDS.
// LAYER1: hbf = elu([A|x]@Bp1 + b1) ; LAYER2: out = log_softmax([A|h]@Bp2+b2)
// ---------------------------------------------------------------------------
template <int LAYER>
__global__ __launch_bounds__(256) void fused_kernel(
        const int* __restrict__ rowstart, const int* __restrict__ deg,
        const unsigned* __restrict__ rec4, const unsigned short* __restrict__ featb,
        const s16x8* __restrict__ Bp, const float* __restrict__ bias,
        unsigned short* __restrict__ hbf, float* __restrict__ out) {
    __shared__ __align__(16) unsigned char sAb[64 * 256];   // 16 KB A-tile
    const int tid = threadIdx.x;
    const int w = tid >> 6, l = tid & 63;
    const int base = blockIdx.x * 64;
    const ushort4* __restrict__ f4 = (const ushort4*)featb;
    const float UQS = 1.0f / 32768.0f;

    // ---- gather phase: 4 passes, 4 concurrent nodes per wave ----
    {
        const int grp = l >> 4;
        const int f   = l & 15;
        #pragma unroll
        for (int pass = 0; pass < 4; ++pass) {
            const int nl   = w * 16 + pass * 4 + grp;
            const int node = base + nl;
            int dg = 0, st = 0;
            if (node < NN) { dg = deg[node]; st = rowstart[node]; }
            float4 sum = make_float4(0.f, 0.f, 0.f, 0.f);
            float4 smu = make_float4(0.f, 0.f, 0.f, 0.f);
            int i = 0;
            for (; i + 8 <= dg; i += 8) {
                #pragma unroll
                for (int jj = 0; jj < 8; ++jj) {
                    const unsigned r = rec4[(size_t)(st + i + jj)];
                    const float u2 = (float)(r >> 17) * UQS;
                    const ushort4 q = f4[(size_t)(r & 0x1FFFFu) * 16 + f];
                    const float vx = bf2f(q.x), vy = bf2f(q.y), vz = bf2f(q.z), vw = bf2f(q.w);
                    sum.x += vx; sum.y += vy; sum.z += vz; sum.w += vw;
                    smu.x = fmaf(u2, vx, smu.x);
                    smu.y = fmaf(u2, vy, smu.y);
                    smu.z = fmaf(u2, vz, smu.z);
                    smu.w = fmaf(u2, vw, smu.w);
                }
            }
            #pragma unroll 4
            for (; i < dg; ++i) {
                const unsigned r = rec4[(size_t)(st + i)];
                const float u2 = (float)(r >> 17) * UQS;
                const ushort4 q = f4[(size_t)(r & 0x1FFFFu) * 16 + f];
                const float vx = bf2f(q.x), vy = bf2f(q.y), vz = bf2f(q.z), vw = bf2f(q.w);
                sum.x += vx; sum.y += vy; sum.z += vz; sum.w += vw;
                smu.x = fmaf(u2, vx, smu.x);
                smu.y = fmaf(u2, vy, smu.y);
                smu.z = fmaf(u2, vz, smu.z);
                smu.w = fmaf(u2, vw, smu.w);
            }
            const float inv = 1.0f / fmaxf((float)dg, 1.0f);
            ushort4 p0, p1;
            p0.x = f2bf((sum.x - smu.x) * inv);
            p0.y = f2bf((sum.y - smu.y) * inv);
            p0.z = f2bf((sum.z - smu.z) * inv);
            p0.w = f2bf((sum.w - smu.w) * inv);
            p1.x = f2bf(smu.x * inv);
            p1.y = f2bf(smu.y * inv);
            p1.z = f2bf(smu.z * inv);
            p1.w = f2bf(smu.w * inv);
            const int swz = (nl & 7) << 4;
            *(ushort4*)(sAb + nl * 256 + ((f * 8) ^ swz))       = p0;
            *(ushort4*)(sAb + nl * 256 + ((128 + f * 8) ^ swz)) = p1;
        }
    }
    __syncthreads();

    // ---- MFMA phase: wave w -> rows w*16..w*16+15 ----
    const int kg  = l >> 4;
    const int row = w * 16 + (l & 15);
    const int swzr = (row & 7) << 4;
    int grow = base + row;
    if (grow >= NN) grow = NN - 1;
    const s16x8* __restrict__ Xr = (const s16x8*)(featb + (size_t)grow * 64);

    s16x8 af[6];
    #pragma unroll
    for (int kb = 0; kb < 4; ++kb)
        af[kb] = *(const s16x8*)(sAb + row * 256 + ((kb * 64 + kg * 16) ^ swzr));
    af[4] = Xr[kg];
    af[5] = Xr[4 + kg];

    if (LAYER == 1) {
        f32x4 acc[4];
        #pragma unroll
        for (int ct = 0; ct < 4; ++ct) acc[ct] = (f32x4){0.f, 0.f, 0.f, 0.f};
        #pragma unroll
        for (int kb = 0; kb < 6; ++kb) {
            #pragma unroll
            for (int ct = 0; ct < 4; ++ct) {
                acc[ct] = __builtin_amdgcn_mfma_f32_16x16x32_bf16(
                    af[kb], Bp[(kb * 4 + ct) * 64 + l], acc[ct], 0, 0, 0);
            }
        }
        const int orow0 = base + w * 16 + kg * 4;
        #pragma unroll
        for (int ct = 0; ct < 4; ++ct) {
            const float bv = bias[ct * 16 + (l & 15)];
            #pragma unroll
            for (int j = 0; j < 4; ++j) {
                float v = acc[ct][j] + bv;
                v = (v > 0.f) ? v : (__expf(v) - 1.f);
                const int r2 = orow0 + j;
                if (r2 < NN) hbf[(size_t)r2 * 64 + ct * 16 + (l & 15)] = f2bf(v);
            }
        }
    } else {
        f32x4 acc[3];
        #pragma unroll
        for (int ct = 0; ct < 3; ++ct) acc[ct] = (f32x4){0.f, 0.f, 0.f, 0.f};
        #pragma unroll
        for (int kb = 0; kb < 6; ++kb) {
            #pragma unroll
            for (int ct = 0; ct < 3; ++ct) {
                acc[ct] = __builtin_amdgcn_mfma_f32_16x16x32_bf16(
                    af[kb], Bp[(kb * 3 + ct) * 64 + l], acc[ct], 0, 0, 0);
            }
        }
        const int col = l & 15;
        const float b0 = bias[col], b1v = bias[16 + col];
        const float b2v = (col < 8) ? bias[32 + col] : 0.f;
        #pragma unroll
        for (int j = 0; j < 4; ++j) {
            const float v0 = acc[0][j] + b0;
            const float v1 = acc[1][j] + b1v;
            const float v2 = (col < 8) ? (acc[2][j] + b2v) : -3.0e38f;
            float m = fmaxf(fmaxf(v0, v1), v2);
            #pragma unroll
            for (int off = 1; off < 16; off <<= 1) m = fmaxf(m, __shfl_xor(m, off, 64));
            float s = __expf(v0 - m) + __expf(v1 - m) + ((col < 8) ? __expf(v2 - m) : 0.f);
            #pragma unroll
            for (int off = 1; off < 16; off <<= 1) s += __shfl_xor(s, off, 64);
            const float lse = m + __logf(s);
            const int r2 = base + w * 16 + kg * 4 + j;
            if (r2 < NN) {
                float* __restrict__ orow = out + (size_t)r2 * 40;
                orow[col]      = v0 - lse;
                orow[16 + col] = v1 - lse;
                if (col < 8) orow[32 + col] = v2 - lse;
            }
        }
    }
}

// ---------------------------------------------------------------------------
extern "C" void kernel_launch(void* const* d_in, const int* in_sizes, int n_in,
                              void* d_out, int out_size, void* d_ws, size_t ws_size,
                              hipStream_t stream) {
    const float* x     = (const float*)d_in[0];
    const int*   ei    = (const int*)  d_in[1];
    const float* u     = (const float*)d_in[2];
    const float* W1    = (const float*)d_in[3];
    const float* root1 = (const float*)d_in[4];
    const float* b1    = (const float*)d_in[5];
    const float* W2    = (const float*)d_in[6];
    const float* root2 = (const float*)d_in[7];
    const float* b2    = (const float*)d_in[8];
    float*       out   = (float*)d_out;

    const int* src = ei;
    const int* dst = ei + NE;

    // ws layout
    char* p = (char*)d_ws;
    int* binCnt   = (int*)p;  p += 4 * 512;
    int* binStart = (int*)p;  p += 4 * 520;
    int* binCur   = (int*)p;  p += 4 * 512;
    int* deg      = (int*)p;  p += (size_t)4 * NN;
    int* rowstart = (int*)p;  p += (size_t)4 * NN;
    ull* brec     = (ull*)p;  p += (size_t)8 * NE;
    unsigned* rec4 = (unsigned*)p;  p += (size_t)4 * NE;
    unsigned short* xbf = (unsigned short*)p;  p += (size_t)2 * NN * 64;
    unsigned short* hbf = (unsigned short*)p;  p += (size_t)2 * NN * 64;
    unsigned short* Bp1 = (unsigned short*)p;  p += (size_t)2 * 6 * 4 * 64 * 8;
    unsigned short* Bp2 = (unsigned short*)p;  p += (size_t)2 * 6 * 3 * 64 * 8;

    hipMemsetAsync(binCnt, 0, 4 * 512, stream);

    const int HIST_B = (NE + 8191) / 8192;           // 196
    prep_kernel<<<CVT_B + 11 + HIST_B, 256, 0, stream>>>(
        x, xbf, W1, root1, Bp1, W2, root2, Bp2, dst, binCnt);
    scan_bins_kernel<<<1, 256, 0, stream>>>(binCnt, binStart, binCur);
    p3_bin_scatter_kernel<<<(NE + 2047) / 2048, 256, 0, stream>>>(src, dst, u, binCur, brec);
    p4_final_kernel<<<NBINS, 256, 0, stream>>>(brec, binStart, deg, rowstart, rec4);

    const int NB = (NN + 63) / 64;
    fused_kernel<1><<<NB, 256, 0, stream>>>(rowstart, deg, rec4, xbf,
                                            (const s16x8*)Bp1, b1, hbf, nullptr);
    fused_kernel<2><<<NB, 256, 0, stream>>>(rowstart, deg, rec4, hbf,
                                            (const s16x8*)Bp2, b2, nullptr, out);
}

// Round 13
// 190.308 us; speedup vs baseline: 1.1603x; 1.1196x over previous
//
#include <hip/hip_runtime.h>
#include <math.h>

#define NN 100000
#define NE 1600000
#define NBINS 391          // bin = dst >> 8
#define CVT_B 6250         // blocks for cvt section of prep
// IN = HID = 64, OUT = 40

typedef unsigned long long ull;
typedef float f32x4 __attribute__((ext_vector_type(4)));
typedef short s16x8 __attribute__((ext_vector_type(8)));

__device__ __forceinline__ unsigned short f2bf(float f) {
    unsigned b = __float_as_uint(f);
    return (unsigned short)((b + 0x7fffu + ((b >> 16) & 1u)) >> 16);
}
__device__ __forceinline__ float bf2f(unsigned short s) {
    return __uint_as_float((unsigned)s << 16);
}

// ---------------------------------------------------------------------------
// prep: [0,CVT_B) x->bf16 | [+6) pack W1|root1 | [+5) pack W2|root2 |
//       [rest) dst bin histogram
// ---------------------------------------------------------------------------
__global__ __launch_bounds__(256) void prep_kernel(
        const float* __restrict__ x, unsigned short* __restrict__ xbf,
        const float* __restrict__ W1, const float* __restrict__ root1,
        unsigned short* __restrict__ Bp1,
        const float* __restrict__ W2, const float* __restrict__ root2,
        unsigned short* __restrict__ Bp2,
        const int* __restrict__ dst, int* __restrict__ binCnt) {
    const int b = blockIdx.x;
    const int t = threadIdx.x;
    if (b < CVT_B) {
        const int i = b * 256 + t;
        if (i < NN * 16) {
            const float4 v = ((const float4*)x)[i];
            ushort4 q;
            q.x = f2bf(v.x); q.y = f2bf(v.y); q.z = f2bf(v.z); q.w = f2bf(v.w);
            ((ushort4*)xbf)[i] = q;
        }
    } else if (b < CVT_B + 6) {
        const int gid = (b - CVT_B) * 256 + t;
        if (gid < 6 * 4 * 64) {
            const int kb = gid >> 8;
            const int ct = (gid >> 6) & 3;
            const int l  = gid & 63;
            const int n  = ct * 16 + (l & 15);
            const int k0 = kb * 32 + (l >> 4) * 8;
            #pragma unroll
            for (int j = 0; j < 8; ++j) {
                const int k = k0 + j;
                const float v = (k < 128) ? W1[k * 64 + n] : root1[(k - 128) * 64 + n];
                Bp1[gid * 8 + j] = f2bf(v);
            }
        }
    } else if (b < CVT_B + 11) {
        const int gid = (b - CVT_B - 6) * 256 + t;
        if (gid < 6 * 3 * 64) {
            const int kb = gid / 192;
            const int r  = gid - kb * 192;
            const int ct = r >> 6;
            const int l  = r & 63;
            const int n  = ct * 16 + (l & 15);
            const int k0 = kb * 32 + (l >> 4) * 8;
            #pragma unroll
            for (int j = 0; j < 8; ++j) {
                const int k = k0 + j;
                float v = 0.f;
                if (n < 40) v = (k < 128) ? W2[k * 40 + n] : root2[(k - 128) * 40 + n];
                Bp2[gid * 8 + j] = f2bf(v);
            }
        }
    } else {
        __shared__ int hist[512];
        hist[t] = 0; hist[t + 256] = 0;
        __syncthreads();
        const int hb = b - (CVT_B + 11);
        const int b4 = hb * 2048;
        #pragma unroll
        for (int k = 0; k < 8; ++k) {
            const int i4 = b4 + k * 256 + t;
            if (i4 * 4 < NE) {
                const int4 d4 = ((const int4*)dst)[i4];
                atomicAdd(&hist[d4.x >> 8], 1);
                atomicAdd(&hist[d4.y >> 8], 1);
                atomicAdd(&hist[d4.z >> 8], 1);
                atomicAdd(&hist[d4.w >> 8], 1);
            }
        }
        __syncthreads();
        if (hist[t])       atomicAdd(&binCnt[t],       hist[t]);
        if (hist[t + 256]) atomicAdd(&binCnt[t + 256], hist[t + 256]);
    }
}

// ---------------------------------------------------------------------------
// scan of binCnt[512] -> binStart[513]; binCur = binStart
// ---------------------------------------------------------------------------
__global__ __launch_bounds__(256) void scan_bins_kernel(
        const int* __restrict__ binCnt, int* __restrict__ binStart,
        int* __restrict__ binCur) {
    __shared__ int sa[512], sb[512];
    const int t = threadIdx.x;
    sa[t] = binCnt[t]; sa[t + 256] = binCnt[t + 256];
    __syncthreads();
    int* cur = sa; int* nxt = sb;
    for (int off = 1; off < 512; off <<= 1) {
        for (int j = t; j < 512; j += 256)
            nxt[j] = cur[j] + ((j >= off) ? cur[j - off] : 0);
        __syncthreads();
        int* tmp = cur; cur = nxt; nxt = tmp;
    }
    for (int j = t; j < 512; j += 256) {
        const int ex = (j == 0) ? 0 : cur[j - 1];
        binStart[j] = ex;
        binCur[j]   = ex;
    }
    if (t == 0) binStart[512] = cur[511];
}

// ---------------------------------------------------------------------------
// p3: binned scatter with LDS reorder -> brec grouped by bin.
// brec = [uq:15|dst:17]<<32 | src.
// ---------------------------------------------------------------------------
__global__ __launch_bounds__(256) void p3_bin_scatter_kernel(
        const int* __restrict__ src, const int* __restrict__ dst,
        const float* __restrict__ u, int* __restrict__ binCur,
        ull* __restrict__ brec) {
    __shared__ int cnt[512], lstart[512], gbase[512], lcur[512];
    __shared__ int sa[512], sb[512];
    __shared__ ull buf[2048];
    const int t = threadIdx.x;
    cnt[t] = 0; cnt[t + 256] = 0;
    __syncthreads();
    const int base = blockIdx.x * 2048;
    int mysrc[8], mydst[8];
    float myu[8];
    #pragma unroll
    for (int k = 0; k < 8; ++k) {
        const int i = base + k * 256 + t;
        if (i < NE) {
            mydst[k] = dst[i]; mysrc[k] = src[i]; myu[k] = u[i];
            atomicAdd(&cnt[mydst[k] >> 8], 1);
        } else {
            mydst[k] = -1;
        }
    }
    __syncthreads();
    sa[t] = cnt[t]; sa[t + 256] = cnt[t + 256];
    __syncthreads();
    int* cur = sa; int* nxt = sb;
    for (int off = 1; off < 512; off <<= 1) {
        for (int j = t; j < 512; j += 256)
            nxt[j] = cur[j] + ((j >= off) ? cur[j - off] : 0);
        __syncthreads();
        int* tmp = cur; cur = nxt; nxt = tmp;
    }
    for (int j = t; j < 512; j += 256) {
        const int ex = (j == 0) ? 0 : cur[j - 1];
        lstart[j] = ex;
        lcur[j]   = ex;
    }
    __syncthreads();
    for (int j = t; j < 512; j += 256) {
        const int c = cnt[j];
        gbase[j] = c ? atomicAdd(&binCur[j], c) : 0;
    }
    #pragma unroll
    for (int k = 0; k < 8; ++k) {
        if (mydst[k] >= 0) {
            const int b = mydst[k] >> 8;
            const int lp = atomicAdd(&lcur[b], 1);
            int uq = (int)(myu[k] * 32768.0f + 0.5f);
            if (uq > 32767) uq = 32767;
            const unsigned hi = ((unsigned)uq << 17) | (unsigned)mydst[k];
            buf[lp] = ((ull)hi << 32) | (unsigned)mysrc[k];
        }
    }
    __syncthreads();
    const int total = lstart[511] + cnt[511];
    for (int i = t; i < total; i += 256) {
        const ull r = buf[i];
        const int d = (int)((unsigned)(r >> 32) & 0x1FFFFu);
        const int b = d >> 8;
        brec[(size_t)(gbase[b] + (i - lstart[b]))] = r;
    }
}

// ---------------------------------------------------------------------------
// p4: per-bin finalize: deg + rowstart + CSR scatter with LDS cursors.
// rec4 = [uq:15]<<17 | src. Bin window L2-local.
// ---------------------------------------------------------------------------
__global__ __launch_bounds__(256) void p4_final_kernel(
        const ull* __restrict__ brec, const int* __restrict__ binStart,
        int* __restrict__ deg, int* __restrict__ rowstart,
        unsigned* __restrict__ rec4) {
    __shared__ int cnt[256], lpos[256], wsum[4];
    const int b = blockIdx.x;
    const int s = binStart[b], e = binStart[b + 1];
    const int t = threadIdx.x;
    cnt[t] = 0;
    __syncthreads();
    for (int i = s + t; i < e; i += 256)
        atomicAdd(&cnt[(unsigned)(brec[i] >> 32) & 0xFFu], 1);
    __syncthreads();
    const int lane = t & 63, w = t >> 6;
    const int v = cnt[t];
    int inc = v;
    for (int off = 1; off < 64; off <<= 1) {
        int tv = __shfl_up(inc, off, 64);
        if (lane >= off) inc += tv;
    }
    if (lane == 63) wsum[w] = inc;
    __syncthreads();
    int add = 0;
    #pragma unroll
    for (int i = 0; i < 4; ++i) if (i < w) add += wsum[i];
    const int excl = add + inc - v;
    const int node = b * 256 + t;
    if (node < NN) {
        deg[node]      = v;
        rowstart[node] = s + excl;
    }
    lpos[t] = s + excl;
    __syncthreads();
    for (int i = s + t; i < e; i += 256) {
        const ull r = brec[i];
        const unsigned hi = (unsigned)(r >> 32);
        const int p = atomicAdd(&lpos[hi & 0xFFu], 1);
        rec4[p] = (hi & 0xFFFE0000u) | (unsigned)(r & 0x1FFFFu);
    }
}

// ---------------------------------------------------------------------------
// fused layer, wave-independent: wave w gathers rows w*16..w*16+15 into its
// PRIVATE 4KB LDS quadrant (XOR-swizzled), then waits only on its own LDS
// queue (s_waitcnt lgkmcnt(0) -- DS ops of a wave complete in order; no
// cross-wave LDS traffic exists) and runs the MFMA update. No __syncthreads.
// LAYER1: hbf = elu([A|x]@Bp1 + b1) ; LAYER2: out = log_softmax([A|h]@Bp2+b2)
// ---------------------------------------------------------------------------
template <int LAYER>
__global__ __launch_bounds__(256, 8) void fused_kernel(
        const int* __restrict__ rowstart, const int* __restrict__ deg,
        const unsigned* __restrict__ rec4, const unsigned short* __restrict__ featb,
        const s16x8* __restrict__ Bp, const float* __restrict__ bias,
        unsigned short* __restrict__ hbf, float* __restrict__ out) {
    __shared__ __align__(16) unsigned char sAb[64 * 256];   // 16 KB, 4KB/wave
    const int tid = threadIdx.x;
    const int w = tid >> 6, l = tid & 63;
    const int base = blockIdx.x * 64;
    unsigned char* __restrict__ sW = sAb + w * 4096;         // wave-private
    const ushort4* __restrict__ f4 = (const ushort4*)featb;
    const float UQS = 1.0f / 32768.0f;

    // ---- gather phase: 4 passes, 4 concurrent nodes per wave ----
    {
        const int grp = l >> 4;
        const int f   = l & 15;
        #pragma unroll
        for (int pass = 0; pass < 4; ++pass) {
            const int nlq  = pass * 4 + grp;          // row within wave tile
            const int node = base + w * 16 + nlq;
            int dg = 0, st = 0;
            if (node < NN) { dg = deg[node]; st = rowstart[node]; }
            float4 sum = make_float4(0.f, 0.f, 0.f, 0.f);
            float4 smu = make_float4(0.f, 0.f, 0.f, 0.f);
            int i = 0;
            for (; i + 8 <= dg; i += 8) {
                #pragma unroll
                for (int jj = 0; jj < 8; ++jj) {
                    const unsigned r = rec4[(size_t)(st + i + jj)];
                    const float u2 = (float)(r >> 17) * UQS;
                    const ushort4 q = f4[(size_t)(r & 0x1FFFFu) * 16 + f];
                    const float vx = bf2f(q.x), vy = bf2f(q.y), vz = bf2f(q.z), vw = bf2f(q.w);
                    sum.x += vx; sum.y += vy; sum.z += vz; sum.w += vw;
                    smu.x = fmaf(u2, vx, smu.x);
                    smu.y = fmaf(u2, vy, smu.y);
                    smu.z = fmaf(u2, vz, smu.z);
                    smu.w = fmaf(u2, vw, smu.w);
                }
            }
            #pragma unroll 4
            for (; i < dg; ++i) {
                const unsigned r = rec4[(size_t)(st + i)];
                const float u2 = (float)(r >> 17) * UQS;
                const ushort4 q = f4[(size_t)(r & 0x1FFFFu) * 16 + f];
                const float vx = bf2f(q.x), vy = bf2f(q.y), vz = bf2f(q.z), vw = bf2f(q.w);
                sum.x += vx; sum.y += vy; sum.z += vz; sum.w += vw;
                smu.x = fmaf(u2, vx, smu.x);
                smu.y = fmaf(u2, vy, smu.y);
                smu.z = fmaf(u2, vz, smu.z);
                smu.w = fmaf(u2, vw, smu.w);
            }
            const float inv = 1.0f / fmaxf((float)dg, 1.0f);
            ushort4 p0, p1;
            p0.x = f2bf((sum.x - smu.x) * inv);
            p0.y = f2bf((sum.y - smu.y) * inv);
            p0.z = f2bf((sum.z - smu.z) * inv);
            p0.w = f2bf((sum.w - smu.w) * inv);
            p1.x = f2bf(smu.x * inv);
            p1.y = f2bf(smu.y * inv);
            p1.z = f2bf(smu.z * inv);
            p1.w = f2bf(smu.w * inv);
            const int swz = (nlq & 7) << 4;
            *(ushort4*)(sW + nlq * 256 + ((f * 8) ^ swz))       = p0;
            *(ushort4*)(sW + nlq * 256 + ((128 + f * 8) ^ swz)) = p1;
        }
    }
    // wave-local drain of own DS queue; fence scheduler so frag reads / MFMAs
    // are not hoisted above it (guide rule #18).
    asm volatile("s_waitcnt lgkmcnt(0)" ::: "memory");
    __builtin_amdgcn_sched_barrier(0);

    // ---- MFMA phase: this wave's rows ----
    const int kg  = l >> 4;
    const int rl  = l & 15;                    // row within wave tile
    const int swzr = (rl & 7) << 4;
    int grow = base + w * 16 + rl;
    if (grow >= NN) grow = NN - 1;
    const s16x8* __restrict__ Xr = (const s16x8*)(featb + (size_t)grow * 64);

    s16x8 af[6];
    #pragma unroll
    for (int kb = 0; kb < 4; ++kb)
        af[kb] = *(const s16x8*)(sW + rl * 256 + ((kb * 64 + kg * 16) ^ swzr));
    af[4] = Xr[kg];
    af[5] = Xr[4 + kg];

    if (LAYER == 1) {
        f32x4 acc[4];
        #pragma unroll
        for (int ct = 0; ct < 4; ++ct) acc[ct] = (f32x4){0.f, 0.f, 0.f, 0.f};
        #pragma unroll
        for (int kb = 0; kb < 6; ++kb) {
            #pragma unroll
            for (int ct = 0; ct < 4; ++ct) {
                acc[ct] = __builtin_amdgcn_mfma_f32_16x16x32_bf16(
                    af[kb], Bp[(kb * 4 + ct) * 64 + l], acc[ct], 0, 0, 0);
            }
        }
        const int orow0 = base + w * 16 + kg * 4;
        #pragma unroll
        for (int ct = 0; ct < 4; ++ct) {
            const float bv = bias[ct * 16 + (l & 15)];
            #pragma unroll
            for (int j = 0; j < 4; ++j) {
                float v = acc[ct][j] + bv;
                v = (v > 0.f) ? v : (__expf(v) - 1.f);
                const int r2 = orow0 + j;
                if (r2 < NN) hbf[(size_t)r2 * 64 + ct * 16 + (l & 15)] = f2bf(v);
            }
        }
    } else {
        f32x4 acc[3];
        #pragma unroll
        for (int ct = 0; ct < 3; ++ct) acc[ct] = (f32x4){0.f, 0.f, 0.f, 0.f};
        #pragma unroll
        for (int kb = 0; kb < 6; ++kb) {
            #pragma unroll
            for (int ct = 0; ct < 3; ++ct) {
                acc[ct] = __builtin_amdgcn_mfma_f32_16x16x32_bf16(
                    af[kb], Bp[(kb * 3 + ct) * 64 + l], acc[ct], 0, 0, 0);
            }
        }
        const int col = l & 15;
        const float b0 = bias[col], b1v = bias[16 + col];
        const float b2v = (col < 8) ? bias[32 + col] : 0.f;
        #pragma unroll
        for (int j = 0; j < 4; ++j) {
            const float v0 = acc[0][j] + b0;
            const float v1 = acc[1][j] + b1v;
            const float v2 = (col < 8) ? (acc[2][j] + b2v) : -3.0e38f;
            float m = fmaxf(fmaxf(v0, v1), v2);
            #pragma unroll
            for (int off = 1; off < 16; off <<= 1) m = fmaxf(m, __shfl_xor(m, off, 64));
            float s = __expf(v0 - m) + __expf(v1 - m) + ((col < 8) ? __expf(v2 - m) : 0.f);
            #pragma unroll
            for (int off = 1; off < 16; off <<= 1) s += __shfl_xor(s, off, 64);
            const float lse = m + __logf(s);
            const int r2 = base + w * 16 + kg * 4 + j;
            if (r2 < NN) {
                float* __restrict__ orow = out + (size_t)r2 * 40;
                orow[col]      = v0 - lse;
                orow[16 + col] = v1 - lse;
                if (col < 8) orow[32 + col] = v2 - lse;
            }
        }
    }
}

// ---------------------------------------------------------------------------
extern "C" void kernel_launch(void* const* d_in, const int* in_sizes, int n_in,
                              void* d_out, int out_size, void* d_ws, size_t ws_size,
                              hipStream_t stream) {
    const float* x     = (const float*)d_in[0];
    const int*   ei    = (const int*)  d_in[1];
    const float* u     = (const float*)d_in[2];
    const float* W1    = (const float*)d_in[3];
    const float* root1 = (const float*)d_in[4];
    const float* b1    = (const float*)d_in[5];
    const float* W2    = (const float*)d_in[6];
    const float* root2 = (const float*)d_in[7];
    const float* b2    = (const float*)d_in[8];
    float*       out   = (float*)d_out;

    const int* src = ei;
    const int* dst = ei + NE;

    // ws layout
    char* p = (char*)d_ws;
    int* binCnt   = (int*)p;  p += 4 * 512;
    int* binStart = (int*)p;  p += 4 * 520;
    int* binCur   = (int*)p;  p += 4 * 512;
    int* deg      = (int*)p;  p += (size_t)4 * NN;
    int* rowstart = (int*)p;  p += (size_t)4 * NN;
    ull* brec     = (ull*)p;  p += (size_t)8 * NE;
    unsigned* rec4 = (unsigned*)p;  p += (size_t)4 * NE;
    unsigned short* xbf = (unsigned short*)p;  p += (size_t)2 * NN * 64;
    unsigned short* hbf = (unsigned short*)p;  p += (size_t)2 * NN * 64;
    unsigned short* Bp1 = (unsigned short*)p;  p += (size_t)2 * 6 * 4 * 64 * 8;
    unsigned short* Bp2 = (unsigned short*)p;  p += (size_t)2 * 6 * 3 * 64 * 8;

    hipMemsetAsync(binCnt, 0, 4 * 512, stream);

    const int HIST_B = (NE + 8191) / 8192;           // 196
    prep_kernel<<<CVT_B + 11 + HIST_B, 256, 0, stream>>>(
        x, xbf, W1, root1, Bp1, W2, root2, Bp2, dst, binCnt);
    scan_bins_kernel<<<1, 256, 0, stream>>>(binCnt, binStart, binCur);
    p3_bin_scatter_kernel<<<(NE + 2047) / 2048, 256, 0, stream>>>(src, dst, u, binCur, brec);
    p4_final_kernel<<<NBINS, 256, 0, stream>>>(brec, binStart, deg, rowstart, rec4);

    const int NB = (NN + 63) / 64;
    fused_kernel<1><<<NB, 256, 0, stream>>>(rowstart, deg, rec4, xbf,
                                            (const s16x8*)Bp1, b1, hbf, nullptr);
    fused_kernel<2><<<NB, 256, 0, stream>>>(rowstart, deg, rec4, hbf,
                                            (const s16x8*)Bp2, b2, nullptr, out);
}

// Round 14
// 159.152 us; speedup vs baseline: 1.3874x; 1.1958x over previous
//
#include <hip/hip_runtime.h>
#include <math.h>

#define NN 100000
#define NE 1600000
#define NBINS 391          // bin = dst >> 8
#define CVT_B 6250         // blocks for cvt section of prep
// IN = HID = 64, OUT = 40

typedef unsigned long long ull;
typedef float f32x4 __attribute__((ext_vector_type(4)));
typedef float f32x2 __attribute__((ext_vector_type(2)));
typedef short s16x8 __attribute__((ext_vector_type(8)));

__device__ __forceinline__ unsigned short f2bf(float f) {
    unsigned b = __float_as_uint(f);
    return (unsigned short)((b + 0x7fffu + ((b >> 16) & 1u)) >> 16);
}
__device__ __forceinline__ float bf2f(unsigned short s) {
    return __uint_as_float((unsigned)s << 16);
}
__device__ __forceinline__ unsigned pack4_fp8(float a, float b, float c, float d) {
    int r = 0;
    r = __builtin_amdgcn_cvt_pk_fp8_f32(a, b, r, false);  // bytes 0,1
    r = __builtin_amdgcn_cvt_pk_fp8_f32(c, d, r, true);   // bytes 2,3
    return (unsigned)r;
}

// ---------------------------------------------------------------------------
// prep: [0,CVT_B) x->bf16 + x->fp8 | [+6) pack W1|root1 | [+5) pack W2|root2
//       | [rest) dst bin histogram
// ---------------------------------------------------------------------------
__global__ __launch_bounds__(256) void prep_kernel(
        const float* __restrict__ x, unsigned short* __restrict__ xbf,
        unsigned* __restrict__ x8,
        const float* __restrict__ W1, const float* __restrict__ root1,
        unsigned short* __restrict__ Bp1,
        const float* __restrict__ W2, const float* __restrict__ root2,
        unsigned short* __restrict__ Bp2,
        const int* __restrict__ dst, int* __restrict__ binCnt) {
    const int b = blockIdx.x;
    const int t = threadIdx.x;
    if (b < CVT_B) {
        const int i = b * 256 + t;
        if (i < NN * 16) {
            const float4 v = ((const float4*)x)[i];
            ushort4 q;
            q.x = f2bf(v.x); q.y = f2bf(v.y); q.z = f2bf(v.z); q.w = f2bf(v.w);
            ((ushort4*)xbf)[i] = q;
            x8[i] = pack4_fp8(v.x, v.y, v.z, v.w);
        }
    } else if (b < CVT_B + 6) {
        const int gid = (b - CVT_B) * 256 + t;
        if (gid < 6 * 4 * 64) {
            const int kb = gid >> 8;
            const int ct = (gid >> 6) & 3;
            const int l  = gid & 63;
            const int n  = ct * 16 + (l & 15);
            const int k0 = kb * 32 + (l >> 4) * 8;
            #pragma unroll
            for (int j = 0; j < 8; ++j) {
                const int k = k0 + j;
                const float v = (k < 128) ? W1[k * 64 + n] : root1[(k - 128) * 64 + n];
                Bp1[gid * 8 + j] = f2bf(v);
            }
        }
    } else if (b < CVT_B + 11) {
        const int gid = (b - CVT_B - 6) * 256 + t;
        if (gid < 6 * 3 * 64) {
            const int kb = gid / 192;
            const int r  = gid - kb * 192;
            const int ct = r >> 6;
            const int l  = r & 63;
            const int n  = ct * 16 + (l & 15);
            const int k0 = kb * 32 + (l >> 4) * 8;
            #pragma unroll
            for (int j = 0; j < 8; ++j) {
                const int k = k0 + j;
                float v = 0.f;
                if (n < 40) v = (k < 128) ? W2[k * 40 + n] : root2[(k - 128) * 40 + n];
                Bp2[gid * 8 + j] = f2bf(v);
            }
        }
    } else {
        __shared__ int hist[512];
        hist[t] = 0; hist[t + 256] = 0;
        __syncthreads();
        const int hb = b - (CVT_B + 11);
        const int b4 = hb * 2048;
        #pragma unroll
        for (int k = 0; k < 8; ++k) {
            const int i4 = b4 + k * 256 + t;
            if (i4 * 4 < NE) {
                const int4 d4 = ((const int4*)dst)[i4];
                atomicAdd(&hist[d4.x >> 8], 1);
                atomicAdd(&hist[d4.y >> 8], 1);
                atomicAdd(&hist[d4.z >> 8], 1);
                atomicAdd(&hist[d4.w >> 8], 1);
            }
        }
        __syncthreads();
        if (hist[t])       atomicAdd(&binCnt[t],       hist[t]);
        if (hist[t + 256]) atomicAdd(&binCnt[t + 256], hist[t + 256]);
    }
}

// ---------------------------------------------------------------------------
// scan of binCnt[512] -> binStart[513]; binCur = binStart
// ---------------------------------------------------------------------------
__global__ __launch_bounds__(256) void scan_bins_kernel(
        const int* __restrict__ binCnt, int* __restrict__ binStart,
        int* __restrict__ binCur) {
    __shared__ int sa[512], sb[512];
    const int t = threadIdx.x;
    sa[t] = binCnt[t]; sa[t + 256] = binCnt[t + 256];
    __syncthreads();
    int* cur = sa; int* nxt = sb;
    for (int off = 1; off < 512; off <<= 1) {
        for (int j = t; j < 512; j += 256)
            nxt[j] = cur[j] + ((j >= off) ? cur[j - off] : 0);
        __syncthreads();
        int* tmp = cur; cur = nxt; nxt = tmp;
    }
    for (int j = t; j < 512; j += 256) {
        const int ex = (j == 0) ? 0 : cur[j - 1];
        binStart[j] = ex;
        binCur[j]   = ex;
    }
    if (t == 0) binStart[512] = cur[511];
}

// ---------------------------------------------------------------------------
// p3: binned scatter with LDS reorder -> brec grouped by bin.
// brec = [uq:15|dst:17]<<32 | src.
// ---------------------------------------------------------------------------
__global__ __launch_bounds__(256) void p3_bin_scatter_kernel(
        const int* __restrict__ src, const int* __restrict__ dst,
        const float* __restrict__ u, int* __restrict__ binCur,
        ull* __restrict__ brec) {
    __shared__ int cnt[512], lstart[512], gbase[512], lcur[512];
    __shared__ int sa[512], sb[512];
    __shared__ ull buf[2048];
    const int t = threadIdx.x;
    cnt[t] = 0; cnt[t + 256] = 0;
    __syncthreads();
    const int base = blockIdx.x * 2048;
    int mysrc[8], mydst[8];
    float myu[8];
    #pragma unroll
    for (int k = 0; k < 8; ++k) {
        const int i = base + k * 256 + t;
        if (i < NE) {
            mydst[k] = dst[i]; mysrc[k] = src[i]; myu[k] = u[i];
            atomicAdd(&cnt[mydst[k] >> 8], 1);
        } else {
            mydst[k] = -1;
        }
    }
    __syncthreads();
    sa[t] = cnt[t]; sa[t + 256] = cnt[t + 256];
    __syncthreads();
    int* cur = sa; int* nxt = sb;
    for (int off = 1; off < 512; off <<= 1) {
        for (int j = t; j < 512; j += 256)
            nxt[j] = cur[j] + ((j >= off) ? cur[j - off] : 0);
        __syncthreads();
        int* tmp = cur; cur = nxt; nxt = tmp;
    }
    for (int j = t; j < 512; j += 256) {
        const int ex = (j == 0) ? 0 : cur[j - 1];
        lstart[j] = ex;
        lcur[j]   = ex;
    }
    __syncthreads();
    for (int j = t; j < 512; j += 256) {
        const int c = cnt[j];
        gbase[j] = c ? atomicAdd(&binCur[j], c) : 0;
    }
    #pragma unroll
    for (int k = 0; k < 8; ++k) {
        if (mydst[k] >= 0) {
            const int b = mydst[k] >> 8;
            const int lp = atomicAdd(&lcur[b], 1);
            int uq = (int)(myu[k] * 32768.0f + 0.5f);
            if (uq > 32767) uq = 32767;
            const unsigned hi = ((unsigned)uq << 17) | (unsigned)mydst[k];
            buf[lp] = ((ull)hi << 32) | (unsigned)mysrc[k];
        }
    }
    __syncthreads();
    const int total = lstart[511] + cnt[511];
    for (int i = t; i < total; i += 256) {
        const ull r = buf[i];
        const int d = (int)((unsigned)(r >> 32) & 0x1FFFFu);
        const int b = d >> 8;
        brec[(size_t)(gbase[b] + (i - lstart[b]))] = r;
    }
}

// ---------------------------------------------------------------------------
// p4: per-bin finalize: deg + rowstart + CSR scatter with LDS cursors.
// rec4 = [uq:15]<<17 | src. Bin window L2-local.
// ---------------------------------------------------------------------------
__global__ __launch_bounds__(256) void p4_final_kernel(
        const ull* __restrict__ brec, const int* __restrict__ binStart,
        int* __restrict__ deg, int* __restrict__ rowstart,
        unsigned* __restrict__ rec4) {
    __shared__ int cnt[256], lpos[256], wsum[4];
    const int b = blockIdx.x;
    const int s = binStart[b], e = binStart[b + 1];
    const int t = threadIdx.x;
    cnt[t] = 0;
    __syncthreads();
    for (int i = s + t; i < e; i += 256)
        atomicAdd(&cnt[(unsigned)(brec[i] >> 32) & 0xFFu], 1);
    __syncthreads();
    const int lane = t & 63, w = t >> 6;
    const int v = cnt[t];
    int inc = v;
    for (int off = 1; off < 64; off <<= 1) {
        int tv = __shfl_up(inc, off, 64);
        if (lane >= off) inc += tv;
    }
    if (lane == 63) wsum[w] = inc;
    __syncthreads();
    int add = 0;
    #pragma unroll
    for (int i = 0; i < 4; ++i) if (i < w) add += wsum[i];
    const int excl = add + inc - v;
    const int node = b * 256 + t;
    if (node < NN) {
        deg[node]      = v;
        rowstart[node] = s + excl;
    }
    lpos[t] = s + excl;
    __syncthreads();
    for (int i = s + t; i < e; i += 256) {
        const ull r = brec[i];
        const unsigned hi = (unsigned)(r >> 32);
        const int p = atomicAdd(&lpos[hi & 0xFFu], 1);
        rec4[p] = (hi & 0xFFFE0000u) | (unsigned)(r & 0x1FFFFu);
    }
}

// ---------------------------------------------------------------------------
// fused layer, wave-independent, fp8 gather: wave w gathers rows w*16..+15
// from the fp8 table (64 B/row, HW cvt decode) into its PRIVATE 4KB LDS
// quadrant (XOR-swizzled bf16 A-tile), drains its own DS queue, then MFMAs.
// LAYER1: hbf = elu([A|x]@Bp1 + b1), also emits h8 (fp8) for layer-2 gather.
// LAYER2: out = log_softmax([A|h]@Bp2 + b2)
// ---------------------------------------------------------------------------
template <int LAYER>
__global__ __launch_bounds__(256, 8) void fused_kernel(
        const int* __restrict__ rowstart, const int* __restrict__ deg,
        const unsigned* __restrict__ rec4, const unsigned* __restrict__ feat8,
        const unsigned short* __restrict__ featb,
        const s16x8* __restrict__ Bp, const float* __restrict__ bias,
        unsigned short* __restrict__ hbf, unsigned char* __restrict__ h8,
        float* __restrict__ out) {
    __shared__ __align__(16) unsigned char sAb[64 * 256];   // 16 KB, 4KB/wave
    const int tid = threadIdx.x;
    const int w = tid >> 6, l = tid & 63;
    const int base = blockIdx.x * 64;
    unsigned char* __restrict__ sW = sAb + w * 4096;         // wave-private
    const float UQS = 1.0f / 32768.0f;

    // ---- gather phase: 4 passes, 4 concurrent nodes per wave ----
    {
        const int grp = l >> 4;
        const int f   = l & 15;
        #pragma unroll
        for (int pass = 0; pass < 4; ++pass) {
            const int nlq  = pass * 4 + grp;          // row within wave tile
            const int node = base + w * 16 + nlq;
            int dg = 0, st = 0;
            if (node < NN) { dg = deg[node]; st = rowstart[node]; }
            float4 sum = make_float4(0.f, 0.f, 0.f, 0.f);
            float4 smu = make_float4(0.f, 0.f, 0.f, 0.f);
            int i = 0;
            for (; i + 8 <= dg; i += 8) {
                #pragma unroll
                for (int jj = 0; jj < 8; ++jj) {
                    const unsigned r = rec4[(size_t)(st + i + jj)];
                    const float u2 = (float)(r >> 17) * UQS;
                    const unsigned q = feat8[(size_t)(r & 0x1FFFFu) * 16 + f];
                    const f32x2 ab = __builtin_amdgcn_cvt_pk_f32_fp8((int)q, false);
                    const f32x2 cd = __builtin_amdgcn_cvt_pk_f32_fp8((int)q, true);
                    sum.x += ab[0]; sum.y += ab[1]; sum.z += cd[0]; sum.w += cd[1];
                    smu.x = fmaf(u2, ab[0], smu.x);
                    smu.y = fmaf(u2, ab[1], smu.y);
                    smu.z = fmaf(u2, cd[0], smu.z);
                    smu.w = fmaf(u2, cd[1], smu.w);
                }
            }
            #pragma unroll 4
            for (; i < dg; ++i) {
                const unsigned r = rec4[(size_t)(st + i)];
                const float u2 = (float)(r >> 17) * UQS;
                const unsigned q = feat8[(size_t)(r & 0x1FFFFu) * 16 + f];
                const f32x2 ab = __builtin_amdgcn_cvt_pk_f32_fp8((int)q, false);
                const f32x2 cd = __builtin_amdgcn_cvt_pk_f32_fp8((int)q, true);
                sum.x += ab[0]; sum.y += ab[1]; sum.z += cd[0]; sum.w += cd[1];
                smu.x = fmaf(u2, ab[0], smu.x);
                smu.y = fmaf(u2, ab[1], smu.y);
                smu.z = fmaf(u2, cd[0], smu.z);
                smu.w = fmaf(u2, cd[1], smu.w);
            }
            const float inv = 1.0f / fmaxf((float)dg, 1.0f);
            ushort4 p0, p1;
            p0.x = f2bf((sum.x - smu.x) * inv);
            p0.y = f2bf((sum.y - smu.y) * inv);
            p0.z = f2bf((sum.z - smu.z) * inv);
            p0.w = f2bf((sum.w - smu.w) * inv);
            p1.x = f2bf(smu.x * inv);
            p1.y = f2bf(smu.y * inv);
            p1.z = f2bf(smu.z * inv);
            p1.w = f2bf(smu.w * inv);
            const int swz = (nlq & 7) << 4;
            *(ushort4*)(sW + nlq * 256 + ((f * 8) ^ swz))       = p0;
            *(ushort4*)(sW + nlq * 256 + ((128 + f * 8) ^ swz)) = p1;
        }
    }
    // wave-local drain of own DS queue; fence scheduler (guide rule #18).
    asm volatile("s_waitcnt lgkmcnt(0)" ::: "memory");
    __builtin_amdgcn_sched_barrier(0);

    // ---- MFMA phase: this wave's rows ----
    const int kg  = l >> 4;
    const int rl  = l & 15;                    // row within wave tile
    const int swzr = (rl & 7) << 4;
    int grow = base + w * 16 + rl;
    if (grow >= NN) grow = NN - 1;
    const s16x8* __restrict__ Xr = (const s16x8*)(featb + (size_t)grow * 64);

    s16x8 af[6];
    #pragma unroll
    for (int kb = 0; kb < 4; ++kb)
        af[kb] = *(const s16x8*)(sW + rl * 256 + ((kb * 64 + kg * 16) ^ swzr));
    af[4] = Xr[kg];
    af[5] = Xr[4 + kg];

    if (LAYER == 1) {
        f32x4 acc[4];
        #pragma unroll
        for (int ct = 0; ct < 4; ++ct) acc[ct] = (f32x4){0.f, 0.f, 0.f, 0.f};
        #pragma unroll
        for (int kb = 0; kb < 6; ++kb) {
            #pragma unroll
            for (int ct = 0; ct < 4; ++ct) {
                acc[ct] = __builtin_amdgcn_mfma_f32_16x16x32_bf16(
                    af[kb], Bp[(kb * 4 + ct) * 64 + l], acc[ct], 0, 0, 0);
            }
        }
        const int orow0 = base + w * 16 + kg * 4;
        #pragma unroll
        for (int ct = 0; ct < 4; ++ct) {
            const float bv = bias[ct * 16 + (l & 15)];
            #pragma unroll
            for (int j = 0; j < 4; ++j) {
                float v = acc[ct][j] + bv;
                v = (v > 0.f) ? v : (__expf(v) - 1.f);
                const int r2 = orow0 + j;
                if (r2 < NN) {
                    hbf[(size_t)r2 * 64 + ct * 16 + (l & 15)] = f2bf(v);
                    const int e8 = __builtin_amdgcn_cvt_pk_fp8_f32(v, v, 0, false);
                    h8[(size_t)r2 * 64 + ct * 16 + (l & 15)] = (unsigned char)(e8 & 0xFF);
                }
            }
        }
    } else {
        f32x4 acc[3];
        #pragma unroll
        for (int ct = 0; ct < 3; ++ct) acc[ct] = (f32x4){0.f, 0.f, 0.f, 0.f};
        #pragma unroll
        for (int kb = 0; kb < 6; ++kb) {
            #pragma unroll
            for (int ct = 0; ct < 3; ++ct) {
                acc[ct] = __builtin_amdgcn_mfma_f32_16x16x32_bf16(
                    af[kb], Bp[(kb * 3 + ct) * 64 + l], acc[ct], 0, 0, 0);
            }
        }
        const int col = l & 15;
        const float b0 = bias[col], b1v = bias[16 + col];
        const float b2v = (col < 8) ? bias[32 + col] : 0.f;
        #pragma unroll
        for (int j = 0; j < 4; ++j) {
            const float v0 = acc[0][j] + b0;
            const float v1 = acc[1][j] + b1v;
            const float v2 = (col < 8) ? (acc[2][j] + b2v) : -3.0e38f;
            float m = fmaxf(fmaxf(v0, v1), v2);
            #pragma unroll
            for (int off = 1; off < 16; off <<= 1) m = fmaxf(m, __shfl_xor(m, off, 64));
            float s = __expf(v0 - m) + __expf(v1 - m) + ((col < 8) ? __expf(v2 - m) : 0.f);
            #pragma unroll
            for (int off = 1; off < 16; off <<= 1) s += __shfl_xor(s, off, 64);
            const float lse = m + __logf(s);
            const int r2 = base + w * 16 + kg * 4 + j;
            if (r2 < NN) {
                float* __restrict__ orow = out + (size_t)r2 * 40;
                orow[col]      = v0 - lse;
                orow[16 + col] = v1 - lse;
                if (col < 8) orow[32 + col] = v2 - lse;
            }
        }
    }
}

// ---------------------------------------------------------------------------
extern "C" void kernel_launch(void* const* d_in, const int* in_sizes, int n_in,
                              void* d_out, int out_size, void* d_ws, size_t ws_size,
                              hipStream_t stream) {
    const float* x     = (const float*)d_in[0];
    const int*   ei    = (const int*)  d_in[1];
    const float* u     = (const float*)d_in[2];
    const float* W1    = (const float*)d_in[3];
    const float* root1 = (const float*)d_in[4];
    const float* b1    = (const float*)d_in[5];
    const float* W2    = (const float*)d_in[6];
    const float* root2 = (const float*)d_in[7];
    const float* b2    = (const float*)d_in[8];
    float*       out   = (float*)d_out;

    const int* src = ei;
    const int* dst = ei + NE;

    // ws layout
    char* p = (char*)d_ws;
    int* binCnt   = (int*)p;  p += 4 * 512;
    int* binStart = (int*)p;  p += 4 * 520;
    int* binCur   = (int*)p;  p += 4 * 512;
    int* deg      = (int*)p;  p += (size_t)4 * NN;
    int* rowstart = (int*)p;  p += (size_t)4 * NN;
    ull* brec     = (ull*)p;  p += (size_t)8 * NE;
    unsigned* rec4 = (unsigned*)p;  p += (size_t)4 * NE;
    unsigned short* xbf = (unsigned short*)p;  p += (size_t)2 * NN * 64;
    unsigned short* hbf = (unsigned short*)p;  p += (size_t)2 * NN * 64;
    unsigned* x8  = (unsigned*)p;  p += (size_t)4 * NN * 16;
    unsigned char* h8 = (unsigned char*)p;  p += (size_t)NN * 64;
    unsigned short* Bp1 = (unsigned short*)p;  p += (size_t)2 * 6 * 4 * 64 * 8;
    unsigned short* Bp2 = (unsigned short*)p;  p += (size_t)2 * 6 * 3 * 64 * 8;

    hipMemsetAsync(binCnt, 0, 4 * 512, stream);

    const int HIST_B = (NE + 8191) / 8192;           // 196
    prep_kernel<<<CVT_B + 11 + HIST_B, 256, 0, stream>>>(
        x, xbf, x8, W1, root1, Bp1, W2, root2, Bp2, dst, binCnt);
    scan_bins_kernel<<<1, 256, 0, stream>>>(binCnt, binStart, binCur);
    p3_bin_scatter_kernel<<<(NE + 2047) / 2048, 256, 0, stream>>>(src, dst, u, binCur, brec);
    p4_final_kernel<<<NBINS, 256, 0, stream>>>(brec, binStart, deg, rowstart, rec4);

    const int NB = (NN + 63) / 64;
    fused_kernel<1><<<NB, 256, 0, stream>>>(rowstart, deg, rec4, x8, xbf,
                                            (const s16x8*)Bp1, b1, hbf, h8, nullptr);
    fused_kernel<2><<<NB, 256, 0, stream>>>(rowstart, deg, rec4, (const unsigned*)h8, hbf,
                                            (const s16x8*)Bp2, b2, nullptr, nullptr, out);
}

// Round 15
// 131.327 us; speedup vs baseline: 1.6814x; 1.2119x over previous
//
#include <hip/hip_runtime.h>
#include <math.h>

#define NN 100000
#define NE 1600000
#define NBINS 391          // bin = dst >> 8
#define BCAP 4608          // padded bin capacity (mean 4092, sigma 64 -> +8 sigma)
#define CVT_B 6250         // blocks for cvt section of prep
// IN = HID = 64, OUT = 40

typedef unsigned long long ull;
typedef float f32x4 __attribute__((ext_vector_type(4)));
typedef float f32x2 __attribute__((ext_vector_type(2)));
typedef short s16x8 __attribute__((ext_vector_type(8)));

__device__ __forceinline__ unsigned short f2bf(float f) {
    unsigned b = __float_as_uint(f);
    return (unsigned short)((b + 0x7fffu + ((b >> 16) & 1u)) >> 16);
}
__device__ __forceinline__ float bf2f(unsigned short s) {
    return __uint_as_float((unsigned)s << 16);
}
__device__ __forceinline__ unsigned pack4_fp8(float a, float b, float c, float d) {
    int r = 0;
    r = __builtin_amdgcn_cvt_pk_fp8_f32(a, b, r, false);  // bytes 0,1
    r = __builtin_amdgcn_cvt_pk_fp8_f32(c, d, r, true);   // bytes 2,3
    return (unsigned)r;
}

// ---------------------------------------------------------------------------
// prep: [0,CVT_B) x->bf16 + x->fp8 | [+6) pack W1|root1 | [+5) pack W2|root2
//       | [+1) init binCur[b] = b*BCAP
// ---------------------------------------------------------------------------
__global__ __launch_bounds__(256) void prep_kernel(
        const float* __restrict__ x, unsigned short* __restrict__ xbf,
        unsigned* __restrict__ x8,
        const float* __restrict__ W1, const float* __restrict__ root1,
        unsigned short* __restrict__ Bp1,
        const float* __restrict__ W2, const float* __restrict__ root2,
        unsigned short* __restrict__ Bp2,
        int* __restrict__ binCur) {
    const int b = blockIdx.x;
    const int t = threadIdx.x;
    if (b < CVT_B) {
        const int i = b * 256 + t;
        if (i < NN * 16) {
            const float4 v = ((const float4*)x)[i];
            ushort4 q;
            q.x = f2bf(v.x); q.y = f2bf(v.y); q.z = f2bf(v.z); q.w = f2bf(v.w);
            ((ushort4*)xbf)[i] = q;
            x8[i] = pack4_fp8(v.x, v.y, v.z, v.w);
        }
    } else if (b < CVT_B + 6) {
        const int gid = (b - CVT_B) * 256 + t;
        if (gid < 6 * 4 * 64) {
            const int kb = gid >> 8;
            const int ct = (gid >> 6) & 3;
            const int l  = gid & 63;
            const int n  = ct * 16 + (l & 15);
            const int k0 = kb * 32 + (l >> 4) * 8;
            #pragma unroll
            for (int j = 0; j < 8; ++j) {
                const int k = k0 + j;
                const float v = (k < 128) ? W1[k * 64 + n] : root1[(k - 128) * 64 + n];
                Bp1[gid * 8 + j] = f2bf(v);
            }
        }
    } else if (b < CVT_B + 11) {
        const int gid = (b - CVT_B - 6) * 256 + t;
        if (gid < 6 * 3 * 64) {
            const int kb = gid / 192;
            const int r  = gid - kb * 192;
            const int ct = r >> 6;
            const int l  = r & 63;
            const int n  = ct * 16 + (l & 15);
            const int k0 = kb * 32 + (l >> 4) * 8;
            #pragma unroll
            for (int j = 0; j < 8; ++j) {
                const int k = k0 + j;
                float v = 0.f;
                if (n < 40) v = (k < 128) ? W2[k * 40 + n] : root2[(k - 128) * 40 + n];
                Bp2[gid * 8 + j] = f2bf(v);
            }
        }
    } else {
        binCur[t]       = t * BCAP;
        binCur[t + 256] = (t + 256) * BCAP;
    }
}

// ---------------------------------------------------------------------------
// p3: binned scatter with LDS reorder -> brec grouped by padded bin.
// brec = [uq:15|dst:17]<<32 | src. binCur pre-initialized to b*BCAP.
// ---------------------------------------------------------------------------
__global__ __launch_bounds__(256) void p3_bin_scatter_kernel(
        const int* __restrict__ src, const int* __restrict__ dst,
        const float* __restrict__ u, int* __restrict__ binCur,
        ull* __restrict__ brec) {
    __shared__ int cnt[512], lstart[512], gbase[512], lcur[512];
    __shared__ int sa[512], sb[512];
    __shared__ ull buf[2048];
    const int t = threadIdx.x;
    cnt[t] = 0; cnt[t + 256] = 0;
    __syncthreads();
    const int base = blockIdx.x * 2048;
    int mysrc[8], mydst[8];
    float myu[8];
    #pragma unroll
    for (int k = 0; k < 8; ++k) {
        const int i = base + k * 256 + t;
        if (i < NE) {
            mydst[k] = dst[i]; mysrc[k] = src[i]; myu[k] = u[i];
            atomicAdd(&cnt[mydst[k] >> 8], 1);
        } else {
            mydst[k] = -1;
        }
    }
    __syncthreads();
    sa[t] = cnt[t]; sa[t + 256] = cnt[t + 256];
    __syncthreads();
    int* cur = sa; int* nxt = sb;
    for (int off = 1; off < 512; off <<= 1) {
        for (int j = t; j < 512; j += 256)
            nxt[j] = cur[j] + ((j >= off) ? cur[j - off] : 0);
        __syncthreads();
        int* tmp = cur; cur = nxt; nxt = tmp;
    }
    for (int j = t; j < 512; j += 256) {
        const int ex = (j == 0) ? 0 : cur[j - 1];
        lstart[j] = ex;
        lcur[j]   = ex;
    }
    __syncthreads();
    for (int j = t; j < 512; j += 256) {
        const int c = cnt[j];
        gbase[j] = c ? atomicAdd(&binCur[j], c) : 0;
    }
    #pragma unroll
    for (int k = 0; k < 8; ++k) {
        if (mydst[k] >= 0) {
            const int b = mydst[k] >> 8;
            const int lp = atomicAdd(&lcur[b], 1);
            int uq = (int)(myu[k] * 32768.0f + 0.5f);
            if (uq > 32767) uq = 32767;
            const unsigned hi = ((unsigned)uq << 17) | (unsigned)mydst[k];
            buf[lp] = ((ull)hi << 32) | (unsigned)mysrc[k];
        }
    }
    __syncthreads();
    const int total = lstart[511] + cnt[511];
    for (int i = t; i < total; i += 256) {
        const ull r = buf[i];
        const int d = (int)((unsigned)(r >> 32) & 0x1FFFFu);
        const int b = d >> 8;
        brec[(size_t)(gbase[b] + (i - lstart[b]))] = r;
    }
}

// ---------------------------------------------------------------------------
// p4: per-bin finalize: deg + rowstart + CSR scatter with LDS cursors.
// Bin b occupies brec[b*BCAP .. binCur[b]). rec4 = [uq:15]<<17 | src.
// ---------------------------------------------------------------------------
__global__ __launch_bounds__(256) void p4_final_kernel(
        const ull* __restrict__ brec, const int* __restrict__ binCur,
        int* __restrict__ deg, int* __restrict__ rowstart,
        unsigned* __restrict__ rec4) {
    __shared__ int cnt[256], lpos[256], wsum[4];
    const int b = blockIdx.x;
    const int s = b * BCAP, e = binCur[b];
    const int t = threadIdx.x;
    cnt[t] = 0;
    __syncthreads();
    for (int i = s + t; i < e; i += 256)
        atomicAdd(&cnt[(unsigned)(brec[i] >> 32) & 0xFFu], 1);
    __syncthreads();
    const int lane = t & 63, w = t >> 6;
    const int v = cnt[t];
    int inc = v;
    for (int off = 1; off < 64; off <<= 1) {
        int tv = __shfl_up(inc, off, 64);
        if (lane >= off) inc += tv;
    }
    if (lane == 63) wsum[w] = inc;
    __syncthreads();
    int add = 0;
    #pragma unroll
    for (int i = 0; i < 4; ++i) if (i < w) add += wsum[i];
    const int excl = add + inc - v;
    const int node = b * 256 + t;
    if (node < NN) {
        deg[node]      = v;
        rowstart[node] = s + excl;
    }
    lpos[t] = s + excl;
    __syncthreads();
    for (int i = s + t; i < e; i += 256) {
        const ull r = brec[i];
        const unsigned hi = (unsigned)(r >> 32);
        const int p = atomicAdd(&lpos[hi & 0xFFu], 1);
        rec4[p] = (hi & 0xFFFE0000u) | (unsigned)(r & 0x1FFFFu);
    }
}

// ---------------------------------------------------------------------------
// fused layer, wave-independent, fp8 gather: wave w gathers rows w*16..+15
// from the fp8 table (64 B/row, HW cvt decode) into its PRIVATE 4KB LDS
// quadrant (XOR-swizzled bf16 A-tile), drains its own DS queue, then MFMAs.
// LAYER1: hbf = elu([A|x]@Bp1 + b1), also emits h8 (fp8) for layer-2 gather.
// LAYER2: out = log_softmax([A|h]@Bp2 + b2)
// ---------------------------------------------------------------------------
template <int LAYER>
__global__ __launch_bounds__(256, 8) void fused_kernel(
        const int* __restrict__ rowstart, const int* __restrict__ deg,
        const unsigned* __restrict__ rec4, const unsigned* __restrict__ feat8,
        const unsigned short* __restrict__ featb,
        const s16x8* __restrict__ Bp, const float* __restrict__ bias,
        unsigned short* __restrict__ hbf, unsigned char* __restrict__ h8,
        float* __restrict__ out) {
    __shared__ __align__(16) unsigned char sAb[64 * 256];   // 16 KB, 4KB/wave
    const int tid = threadIdx.x;
    const int w = tid >> 6, l = tid & 63;
    const int base = blockIdx.x * 64;
    unsigned char* __restrict__ sW = sAb + w * 4096;         // wave-private
    const float UQS = 1.0f / 32768.0f;

    // ---- gather phase: 4 passes, 4 concurrent nodes per wave ----
    {
        const int grp = l >> 4;
        const int f   = l & 15;
        #pragma unroll
        for (int pass = 0; pass < 4; ++pass) {
            const int nlq  = pass * 4 + grp;          // row within wave tile
            const int node = base + w * 16 + nlq;
            int dg = 0, st = 0;
            if (node < NN) { dg = deg[node]; st = rowstart[node]; }
            float4 sum = make_float4(0.f, 0.f, 0.f, 0.f);
            float4 smu = make_float4(0.f, 0.f, 0.f, 0.f);
            int i = 0;
            for (; i + 8 <= dg; i += 8) {
                #pragma unroll
                for (int jj = 0; jj < 8; ++jj) {
                    const unsigned r = rec4[(size_t)(st + i + jj)];
                    const float u2 = (float)(r >> 17) * UQS;
                    const unsigned q = feat8[(size_t)(r & 0x1FFFFu) * 16 + f];
                    const f32x2 ab = __builtin_amdgcn_cvt_pk_f32_fp8((int)q, false);
                    const f32x2 cd = __builtin_amdgcn_cvt_pk_f32_fp8((int)q, true);
                    sum.x += ab[0]; sum.y += ab[1]; sum.z += cd[0]; sum.w += cd[1];
                    smu.x = fmaf(u2, ab[0], smu.x);
                    smu.y = fmaf(u2, ab[1], smu.y);
                    smu.z = fmaf(u2, cd[0], smu.z);
                    smu.w = fmaf(u2, cd[1], smu.w);
                }
            }
            #pragma unroll 4
            for (; i < dg; ++i) {
                const unsigned r = rec4[(size_t)(st + i)];
                const float u2 = (float)(r >> 17) * UQS;
                const unsigned q = feat8[(size_t)(r & 0x1FFFFu) * 16 + f];
                const f32x2 ab = __builtin_amdgcn_cvt_pk_f32_fp8((int)q, false);
                const f32x2 cd = __builtin_amdgcn_cvt_pk_f32_fp8((int)q, true);
                sum.x += ab[0]; sum.y += ab[1]; sum.z += cd[0]; sum.w += cd[1];
                smu.x = fmaf(u2, ab[0], smu.x);
                smu.y = fmaf(u2, ab[1], smu.y);
                smu.z = fmaf(u2, cd[0], smu.z);
                smu.w = fmaf(u2, cd[1], smu.w);
            }
            const float inv = 1.0f / fmaxf((float)dg, 1.0f);
            ushort4 p0, p1;
            p0.x = f2bf((sum.x - smu.x) * inv);
            p0.y = f2bf((sum.y - smu.y) * inv);
            p0.z = f2bf((sum.z - smu.z) * inv);
            p0.w = f2bf((sum.w - smu.w) * inv);
            p1.x = f2bf(smu.x * inv);
            p1.y = f2bf(smu.y * inv);
            p1.z = f2bf(smu.z * inv);
            p1.w = f2bf(smu.w * inv);
            const int swz = (nlq & 7) << 4;
            *(ushort4*)(sW + nlq * 256 + ((f * 8) ^ swz))       = p0;
            *(ushort4*)(sW + nlq * 256 + ((128 + f * 8) ^ swz)) = p1;
        }
    }
    // wave-local drain of own DS queue; fence scheduler (guide rule #18).
    asm volatile("s_waitcnt lgkmcnt(0)" ::: "memory");
    __builtin_amdgcn_sched_barrier(0);

    // ---- MFMA phase: this wave's rows ----
    const int kg  = l >> 4;
    const int rl  = l & 15;                    // row within wave tile
    const int swzr = (rl & 7) << 4;
    int grow = base + w * 16 + rl;
    if (grow >= NN) grow = NN - 1;
    const s16x8* __restrict__ Xr = (const s16x8*)(featb + (size_t)grow * 64);

    s16x8 af[6];
    #pragma unroll
    for (int kb = 0; kb < 4; ++kb)
        af[kb] = *(const s16x8*)(sW + rl * 256 + ((kb * 64 + kg * 16) ^ swzr));
    af[4] = Xr[kg];
    af[5] = Xr[4 + kg];

    if (LAYER == 1) {
        f32x4 acc[4];
        #pragma unroll
        for (int ct = 0; ct < 4; ++ct) acc[ct] = (f32x4){0.f, 0.f, 0.f, 0.f};
        #pragma unroll
        for (int kb = 0; kb < 6; ++kb) {
            #pragma unroll
            for (int ct = 0; ct < 4; ++ct) {
                acc[ct] = __builtin_amdgcn_mfma_f32_16x16x32_bf16(
                    af[kb], Bp[(kb * 4 + ct) * 64 + l], acc[ct], 0, 0, 0);
            }
        }
        const int orow0 = base + w * 16 + kg * 4;
        #pragma unroll
        for (int ct = 0; ct < 4; ++ct) {
            const float bv = bias[ct * 16 + (l & 15)];
            #pragma unroll
            for (int j = 0; j < 4; ++j) {
                float v = acc[ct][j] + bv;
                v = (v > 0.f) ? v : (__expf(v) - 1.f);
                const int r2 = orow0 + j;
                if (r2 < NN) {
                    hbf[(size_t)r2 * 64 + ct * 16 + (l & 15)] = f2bf(v);
                    const int e8 = __builtin_amdgcn_cvt_pk_fp8_f32(v, v, 0, false);
                    h8[(size_t)r2 * 64 + ct * 16 + (l & 15)] = (unsigned char)(e8 & 0xFF);
                }
            }
        }
    } else {
        f32x4 acc[3];
        #pragma unroll
        for (int ct = 0; ct < 3; ++ct) acc[ct] = (f32x4){0.f, 0.f, 0.f, 0.f};
        #pragma unroll
        for (int kb = 0; kb < 6; ++kb) {
            #pragma unroll
            for (int ct = 0; ct < 3; ++ct) {
                acc[ct] = __builtin_amdgcn_mfma_f32_16x16x32_bf16(
                    af[kb], Bp[(kb * 3 + ct) * 64 + l], acc[ct], 0, 0, 0);
            }
        }
        const int col = l & 15;
        const float b0 = bias[col], b1v = bias[16 + col];
        const float b2v = (col < 8) ? bias[32 + col] : 0.f;
        #pragma unroll
        for (int j = 0; j < 4; ++j) {
            const float v0 = acc[0][j] + b0;
            const float v1 = acc[1][j] + b1v;
            const float v2 = (col < 8) ? (acc[2][j] + b2v) : -3.0e38f;
            float m = fmaxf(fmaxf(v0, v1), v2);
            #pragma unroll
            for (int off = 1; off < 16; off <<= 1) m = fmaxf(m, __shfl_xor(m, off, 64));
            float s = __expf(v0 - m) + __expf(v1 - m) + ((col < 8) ? __expf(v2 - m) : 0.f);
            #pragma unroll
            for (int off = 1; off < 16; off <<= 1) s += __shfl_xor(s, off, 64);
            const float lse = m + __logf(s);
            const int r2 = base + w * 16 + kg * 4 + j;
            if (r2 < NN) {
                float* __restrict__ orow = out + (size_t)r2 * 40;
                orow[col]      = v0 - lse;
                orow[16 + col] = v1 - lse;
                if (col < 8) orow[32 + col] = v2 - lse;
            }
        }
    }
}

// ---------------------------------------------------------------------------
extern "C" void kernel_launch(void* const* d_in, const int* in_sizes, int n_in,
                              void* d_out, int out_size, void* d_ws, size_t ws_size,
                              hipStream_t stream) {
    const float* x     = (const float*)d_in[0];
    const int*   ei    = (const int*)  d_in[1];
    const float* u     = (const float*)d_in[2];
    const float* W1    = (const float*)d_in[3];
    const float* root1 = (const float*)d_in[4];
    const float* b1    = (const float*)d_in[5];
    const float* W2    = (const float*)d_in[6];
    const float* root2 = (const float*)d_in[7];
    const float* b2    = (const float*)d_in[8];
    float*       out   = (float*)d_out;

    const int* src = ei;
    const int* dst = ei + NE;

    // ws layout (padded bins: brec/rec4 sized NBINS*BCAP)
    char* p = (char*)d_ws;
    int* binCur   = (int*)p;  p += 4 * 512;
    int* deg      = (int*)p;  p += (size_t)4 * NN;
    int* rowstart = (int*)p;  p += (size_t)4 * NN;
    ull* brec     = (ull*)p;  p += (size_t)8 * NBINS * BCAP;
    unsigned* rec4 = (unsigned*)p;  p += (size_t)4 * NBINS * BCAP;
    unsigned short* xbf = (unsigned short*)p;  p += (size_t)2 * NN * 64;
    unsigned short* hbf = (unsigned short*)p;  p += (size_t)2 * NN * 64;
    unsigned* x8  = (unsigned*)p;  p += (size_t)4 * NN * 16;
    unsigned char* h8 = (unsigned char*)p;  p += (size_t)NN * 64;
    unsigned short* Bp1 = (unsigned short*)p;  p += (size_t)2 * 6 * 4 * 64 * 8;
    unsigned short* Bp2 = (unsigned short*)p;  p += (size_t)2 * 6 * 3 * 64 * 8;

    prep_kernel<<<CVT_B + 12, 256, 0, stream>>>(
        x, xbf, x8, W1, root1, Bp1, W2, root2, Bp2, binCur);
    p3_bin_scatter_kernel<<<(NE + 2047) / 2048, 256, 0, stream>>>(src, dst, u, binCur, brec);
    p4_final_kernel<<<NBINS, 256, 0, stream>>>(brec, binCur, deg, rowstart, rec4);

    const int NB = (NN + 63) / 64;
    fused_kernel<1><<<NB, 256, 0, stream>>>(rowstart, deg, rec4, x8, xbf,
                                            (const s16x8*)Bp1, b1, hbf, h8, nullptr);
    fused_kernel<2><<<NB, 256, 0, stream>>>(rowstart, deg, rec4, (const unsigned*)h8, hbf,
                                            (const s16x8*)Bp2, b2, nullptr, nullptr, out);
}

// Round 16
// 120.736 us; speedup vs baseline: 1.8289x; 1.0877x over previous
//
#include <hip/hip_runtime.h>
#include <math.h>

#define NN 100000
#define NE 1600000
#define NBINS 391          // bin = dst >> 8
#define BCAP 4608          // padded bin capacity (mean 4092, sigma 64 -> +8 sigma)
#define CVT_B 6250         // blocks for cvt section of prep
// IN = HID = 64, OUT = 40

typedef unsigned long long ull;
typedef float f32x4 __attribute__((ext_vector_type(4)));
typedef float f32x2 __attribute__((ext_vector_type(2)));
typedef short s16x8 __attribute__((ext_vector_type(8)));

__device__ __forceinline__ unsigned short f2bf(float f) {
    unsigned b = __float_as_uint(f);
    return (unsigned short)((b + 0x7fffu + ((b >> 16) & 1u)) >> 16);
}
__device__ __forceinline__ float bf2f(unsigned short s) {
    return __uint_as_float((unsigned)s << 16);
}
__device__ __forceinline__ unsigned pack4_fp8(float a, float b, float c, float d) {
    int r = 0;
    r = __builtin_amdgcn_cvt_pk_fp8_f32(a, b, r, false);  // bytes 0,1
    r = __builtin_amdgcn_cvt_pk_fp8_f32(c, d, r, true);   // bytes 2,3
    return (unsigned)r;
}

// ---------------------------------------------------------------------------
// prep: [0,CVT_B) x->bf16 + x->fp8 | [+6) pack W1|root1 | [+5) pack W2|root2
//       | [+1) init binCur[b] = b*BCAP
// ---------------------------------------------------------------------------
__global__ __launch_bounds__(256) void prep_kernel(
        const float* __restrict__ x, unsigned short* __restrict__ xbf,
        unsigned* __restrict__ x8,
        const float* __restrict__ W1, const float* __restrict__ root1,
        unsigned short* __restrict__ Bp1,
        const float* __restrict__ W2, const float* __restrict__ root2,
        unsigned short* __restrict__ Bp2,
        int* __restrict__ binCur) {
    const int b = blockIdx.x;
    const int t = threadIdx.x;
    if (b < CVT_B) {
        const int i = b * 256 + t;
        if (i < NN * 16) {
            const float4 v = ((const float4*)x)[i];
            ushort4 q;
            q.x = f2bf(v.x); q.y = f2bf(v.y); q.z = f2bf(v.z); q.w = f2bf(v.w);
            ((ushort4*)xbf)[i] = q;
            x8[i] = pack4_fp8(v.x, v.y, v.z, v.w);
        }
    } else if (b < CVT_B + 6) {
        const int gid = (b - CVT_B) * 256 + t;
        if (gid < 6 * 4 * 64) {
            const int kb = gid >> 8;
            const int ct = (gid >> 6) & 3;
            const int l  = gid & 63;
            const int n  = ct * 16 + (l & 15);
            const int k0 = kb * 32 + (l >> 4) * 8;
            #pragma unroll
            for (int j = 0; j < 8; ++j) {
                const int k = k0 + j;
                const float v = (k < 128) ? W1[k * 64 + n] : root1[(k - 128) * 64 + n];
                Bp1[gid * 8 + j] = f2bf(v);
            }
        }
    } else if (b < CVT_B + 11) {
        const int gid = (b - CVT_B - 6) * 256 + t;
        if (gid < 6 * 3 * 64) {
            const int kb = gid / 192;
            const int r  = gid - kb * 192;
            const int ct = r >> 6;
            const int l  = r & 63;
            const int n  = ct * 16 + (l & 15);
            const int k0 = kb * 32 + (l >> 4) * 8;
            #pragma unroll
            for (int j = 0; j < 8; ++j) {
                const int k = k0 + j;
                float v = 0.f;
                if (n < 40) v = (k < 128) ? W2[k * 40 + n] : root2[(k - 128) * 40 + n];
                Bp2[gid * 8 + j] = f2bf(v);
            }
        }
    } else {
        binCur[t]       = t * BCAP;
        binCur[t + 256] = (t + 256) * BCAP;
    }
}

// ---------------------------------------------------------------------------
// p3: binned scatter with LDS reorder -> brec grouped by padded bin.
// brec = [uq:15|dst:17]<<32 | src. binCur pre-initialized to b*BCAP.
// ---------------------------------------------------------------------------
__global__ __launch_bounds__(256) void p3_bin_scatter_kernel(
        const int* __restrict__ src, const int* __restrict__ dst,
        const float* __restrict__ u, int* __restrict__ binCur,
        ull* __restrict__ brec) {
    __shared__ int cnt[512], lstart[512], gbase[512], lcur[512];
    __shared__ int sa[512], sb[512];
    __shared__ ull buf[2048];
    const int t = threadIdx.x;
    cnt[t] = 0; cnt[t + 256] = 0;
    __syncthreads();
    const int base = blockIdx.x * 2048;
    int mysrc[8], mydst[8];
    float myu[8];
    #pragma unroll
    for (int k = 0; k < 8; ++k) {
        const int i = base + k * 256 + t;
        if (i < NE) {
            mydst[k] = dst[i]; mysrc[k] = src[i]; myu[k] = u[i];
            atomicAdd(&cnt[mydst[k] >> 8], 1);
        } else {
            mydst[k] = -1;
        }
    }
    __syncthreads();
    sa[t] = cnt[t]; sa[t + 256] = cnt[t + 256];
    __syncthreads();
    int* cur = sa; int* nxt = sb;
    for (int off = 1; off < 512; off <<= 1) {
        for (int j = t; j < 512; j += 256)
            nxt[j] = cur[j] + ((j >= off) ? cur[j - off] : 0);
        __syncthreads();
        int* tmp = cur; cur = nxt; nxt = tmp;
    }
    for (int j = t; j < 512; j += 256) {
        const int ex = (j == 0) ? 0 : cur[j - 1];
        lstart[j] = ex;
        lcur[j]   = ex;
    }
    __syncthreads();
    for (int j = t; j < 512; j += 256) {
        const int c = cnt[j];
        gbase[j] = c ? atomicAdd(&binCur[j], c) : 0;
    }
    #pragma unroll
    for (int k = 0; k < 8; ++k) {
        if (mydst[k] >= 0) {
            const int b = mydst[k] >> 8;
            const int lp = atomicAdd(&lcur[b], 1);
            int uq = (int)(myu[k] * 32768.0f + 0.5f);
            if (uq > 32767) uq = 32767;
            const unsigned hi = ((unsigned)uq << 17) | (unsigned)mydst[k];
            buf[lp] = ((ull)hi << 32) | (unsigned)mysrc[k];
        }
    }
    __syncthreads();
    const int total = lstart[511] + cnt[511];
    for (int i = t; i < total; i += 256) {
        const ull r = buf[i];
        const int d = (int)((unsigned)(r >> 32) & 0x1FFFFu);
        const int b = d >> 8;
        brec[(size_t)(gbase[b] + (i - lstart[b]))] = r;
    }
}

// ---------------------------------------------------------------------------
// p4: per-bin finalize: deg + rowstart + CSR scatter with LDS cursors.
// Bin b occupies brec[b*BCAP .. binCur[b]). rec4 = [uq:15]<<17 | src.
// ---------------------------------------------------------------------------
__global__ __launch_bounds__(256) void p4_final_kernel(
        const ull* __restrict__ brec, const int* __restrict__ binCur,
        int* __restrict__ deg, int* __restrict__ rowstart,
        unsigned* __restrict__ rec4) {
    __shared__ int cnt[256], lpos[256], wsum[4];
    const int b = blockIdx.x;
    const int s = b * BCAP, e = binCur[b];
    const int t = threadIdx.x;
    cnt[t] = 0;
    __syncthreads();
    for (int i = s + t; i < e; i += 256)
        atomicAdd(&cnt[(unsigned)(brec[i] >> 32) & 0xFFu], 1);
    __syncthreads();
    const int lane = t & 63, w = t >> 6;
    const int v = cnt[t];
    int inc = v;
    for (int off = 1; off < 64; off <<= 1) {
        int tv = __shfl_up(inc, off, 64);
        if (lane >= off) inc += tv;
    }
    if (lane == 63) wsum[w] = inc;
    __syncthreads();
    int add = 0;
    #pragma unroll
    for (int i = 0; i < 4; ++i) if (i < w) add += wsum[i];
    const int excl = add + inc - v;
    const int node = b * 256 + t;
    if (node < NN) {
        deg[node]      = v;
        rowstart[node] = s + excl;
    }
    lpos[t] = s + excl;
    __syncthreads();
    for (int i = s + t; i < e; i += 256) {
        const ull r = brec[i];
        const unsigned hi = (unsigned)(r >> 32);
        const int p = atomicAdd(&lpos[hi & 0xFFu], 1);
        rec4[p] = (hi & 0xFFFE0000u) | (unsigned)(r & 0x1FFFFu);
    }
}

// ---------------------------------------------------------------------------
// fused layer, 1 wave per 16-node tile, fp8 gather with 8 lanes/node (uint2
// loads): 2 passes x 8 concurrent nodes per wave -> 2x edges in flight and
// half the serial steps of the 16-lane variant. Aggregates into a 4KB
// XOR-swizzled LDS tile, drains own DS queue, then MFMAs.
// LAYER1: hbf = elu([A|x]@Bp1 + b1), also emits h8 (fp8) for layer-2 gather.
// LAYER2: out = log_softmax([A|h]@Bp2 + b2)
// ---------------------------------------------------------------------------
template <int LAYER>
__global__ __launch_bounds__(64, 8) void fused_kernel(
        const int* __restrict__ rowstart, const int* __restrict__ deg,
        const unsigned* __restrict__ rec4, const unsigned* __restrict__ feat8,
        const unsigned short* __restrict__ featb,
        const s16x8* __restrict__ Bp, const float* __restrict__ bias,
        unsigned short* __restrict__ hbf, unsigned char* __restrict__ h8,
        float* __restrict__ out) {
    __shared__ __align__(16) unsigned char sW[16 * 256];   // 4 KB per wave
    const int l = threadIdx.x;
    const int base = blockIdx.x * 16;
    const uint2* __restrict__ f8v = (const uint2*)feat8;   // row = 8 x uint2
    const float UQS = 1.0f / 32768.0f;

    // ---- gather phase: 2 passes, 8 concurrent nodes per wave ----
    {
        const int grp = l >> 3;     // node slot 0..7
        const int f   = l & 7;      // uint2 feature slot (8 feats)
        #pragma unroll
        for (int pass = 0; pass < 2; ++pass) {
            const int nlq  = pass * 8 + grp;          // row within wave tile
            const int node = base + nlq;
            int dg = 0, st = 0;
            if (node < NN) { dg = deg[node]; st = rowstart[node]; }
            float sum[8], smu[8];
            #pragma unroll
            for (int k = 0; k < 8; ++k) { sum[k] = 0.f; smu[k] = 0.f; }
            int i = 0;
            for (; i + 4 <= dg; i += 4) {
                #pragma unroll
                for (int jj = 0; jj < 4; ++jj) {
                    const unsigned r = rec4[(size_t)(st + i + jj)];
                    const float u2 = (float)(r >> 17) * UQS;
                    const uint2 q2 = f8v[(size_t)(r & 0x1FFFFu) * 8 + f];
                    const f32x2 a0 = __builtin_amdgcn_cvt_pk_f32_fp8((int)q2.x, false);
                    const f32x2 a1 = __builtin_amdgcn_cvt_pk_f32_fp8((int)q2.x, true);
                    const f32x2 b0 = __builtin_amdgcn_cvt_pk_f32_fp8((int)q2.y, false);
                    const f32x2 b1 = __builtin_amdgcn_cvt_pk_f32_fp8((int)q2.y, true);
                    const float v0 = a0[0], v1 = a0[1], v2 = a1[0], v3 = a1[1];
                    const float v4 = b0[0], v5 = b0[1], v6 = b1[0], v7 = b1[1];
                    sum[0] += v0; sum[1] += v1; sum[2] += v2; sum[3] += v3;
                    sum[4] += v4; sum[5] += v5; sum[6] += v6; sum[7] += v7;
                    smu[0] = fmaf(u2, v0, smu[0]); smu[1] = fmaf(u2, v1, smu[1]);
                    smu[2] = fmaf(u2, v2, smu[2]); smu[3] = fmaf(u2, v3, smu[3]);
                    smu[4] = fmaf(u2, v4, smu[4]); smu[5] = fmaf(u2, v5, smu[5]);
                    smu[6] = fmaf(u2, v6, smu[6]); smu[7] = fmaf(u2, v7, smu[7]);
                }
            }
            for (; i < dg; ++i) {
                const unsigned r = rec4[(size_t)(st + i)];
                const float u2 = (float)(r >> 17) * UQS;
                const uint2 q2 = f8v[(size_t)(r & 0x1FFFFu) * 8 + f];
                const f32x2 a0 = __builtin_amdgcn_cvt_pk_f32_fp8((int)q2.x, false);
                const f32x2 a1 = __builtin_amdgcn_cvt_pk_f32_fp8((int)q2.x, true);
                const f32x2 b0 = __builtin_amdgcn_cvt_pk_f32_fp8((int)q2.y, false);
                const f32x2 b1 = __builtin_amdgcn_cvt_pk_f32_fp8((int)q2.y, true);
                const float v0 = a0[0], v1 = a0[1], v2 = a1[0], v3 = a1[1];
                const float v4 = b0[0], v5 = b0[1], v6 = b1[0], v7 = b1[1];
                sum[0] += v0; sum[1] += v1; sum[2] += v2; sum[3] += v3;
                sum[4] += v4; sum[5] += v5; sum[6] += v6; sum[7] += v7;
                smu[0] = fmaf(u2, v0, smu[0]); smu[1] = fmaf(u2, v1, smu[1]);
                smu[2] = fmaf(u2, v2, smu[2]); smu[3] = fmaf(u2, v3, smu[3]);
                smu[4] = fmaf(u2, v4, smu[4]); smu[5] = fmaf(u2, v5, smu[5]);
                smu[6] = fmaf(u2, v6, smu[6]); smu[7] = fmaf(u2, v7, smu[7]);
            }
            const float inv = 1.0f / fmaxf((float)dg, 1.0f);
            s16x8 p0, p1;
            #pragma unroll
            for (int k = 0; k < 8; ++k) {
                p0[k] = (short)f2bf((sum[k] - smu[k]) * inv);
                p1[k] = (short)f2bf(smu[k] * inv);
            }
            const int swz = (nlq & 7) << 4;
            *(s16x8*)(sW + nlq * 256 + ((f * 16) ^ swz))         = p0;
            *(s16x8*)(sW + nlq * 256 + 128 + ((f * 16) ^ swz))   = p1;
        }
    }
    // wave-local drain of own DS queue; fence scheduler (guide rule #18).
    asm volatile("s_waitcnt lgkmcnt(0)" ::: "memory");
    __builtin_amdgcn_sched_barrier(0);

    // ---- MFMA phase: this wave's 16 rows ----
    const int kg = l >> 4;
    const int rl = l & 15;                    // row within wave tile
    const int swzr = (rl & 7) << 4;
    int grow = base + rl;
    if (grow >= NN) grow = NN - 1;
    const s16x8* __restrict__ Xr = (const s16x8*)(featb + (size_t)grow * 64);

    s16x8 af[6];
    #pragma unroll
    for (int kb = 0; kb < 2; ++kb)
        af[kb] = *(const s16x8*)(sW + rl * 256 + ((kb * 64 + kg * 16) ^ swzr));
    #pragma unroll
    for (int kb = 2; kb < 4; ++kb)
        af[kb] = *(const s16x8*)(sW + rl * 256 + 128 + (((kb - 2) * 64 + kg * 16) ^ swzr));
    af[4] = Xr[kg];
    af[5] = Xr[4 + kg];

    if (LAYER == 1) {
        f32x4 acc[4];
        #pragma unroll
        for (int ct = 0; ct < 4; ++ct) acc[ct] = (f32x4){0.f, 0.f, 0.f, 0.f};
        #pragma unroll
        for (int kb = 0; kb < 6; ++kb) {
            #pragma unroll
            for (int ct = 0; ct < 4; ++ct) {
                acc[ct] = __builtin_amdgcn_mfma_f32_16x16x32_bf16(
                    af[kb], Bp[(kb * 4 + ct) * 64 + l], acc[ct], 0, 0, 0);
            }
        }
        const int orow0 = base + kg * 4;
        #pragma unroll
        for (int ct = 0; ct < 4; ++ct) {
            const float bv = bias[ct * 16 + (l & 15)];
            #pragma unroll
            for (int j = 0; j < 4; ++j) {
                float v = acc[ct][j] + bv;
                v = (v > 0.f) ? v : (__expf(v) - 1.f);
                const int r2 = orow0 + j;
                if (r2 < NN) {
                    hbf[(size_t)r2 * 64 + ct * 16 + (l & 15)] = f2bf(v);
                    const int e8 = __builtin_amdgcn_cvt_pk_fp8_f32(v, v, 0, false);
                    h8[(size_t)r2 * 64 + ct * 16 + (l & 15)] = (unsigned char)(e8 & 0xFF);
                }
            }
        }
    } else {
        f32x4 acc[3];
        #pragma unroll
        for (int ct = 0; ct < 3; ++ct) acc[ct] = (f32x4){0.f, 0.f, 0.f, 0.f};
        #pragma unroll
        for (int kb = 0; kb < 6; ++kb) {
            #pragma unroll
            for (int ct = 0; ct < 3; ++ct) {
                acc[ct] = __builtin_amdgcn_mfma_f32_16x16x32_bf16(
                    af[kb], Bp[(kb * 3 + ct) * 64 + l], acc[ct], 0, 0, 0);
            }
        }
        const int col = l & 15;
        const float b0 = bias[col], b1v = bias[16 + col];
        const float b2v = (col < 8) ? bias[32 + col] : 0.f;
        #pragma unroll
        for (int j = 0; j < 4; ++j) {
            const float v0 = acc[0][j] + b0;
            const float v1 = acc[1][j] + b1v;
            const float v2 = (col < 8) ? (acc[2][j] + b2v) : -3.0e38f;
            float m = fmaxf(fmaxf(v0, v1), v2);
            #pragma unroll
            for (int off = 1; off < 16; off <<= 1) m = fmaxf(m, __shfl_xor(m, off, 64));
            float s = __expf(v0 - m) + __expf(v1 - m) + ((col < 8) ? __expf(v2 - m) : 0.f);
            #pragma unroll
            for (int off = 1; off < 16; off <<= 1) s += __shfl_xor(s, off, 64);
            const float lse = m + __logf(s);
            const int r2 = base + kg * 4 + j;
            if (r2 < NN) {
                float* __restrict__ orow = out + (size_t)r2 * 40;
                orow[col]      = v0 - lse;
                orow[16 + col] = v1 - lse;
                if (col < 8) orow[32 + col] = v2 - lse;
            }
        }
    }
}

// ---------------------------------------------------------------------------
extern "C" void kernel_launch(void* const* d_in, const int* in_sizes, int n_in,
                              void* d_out, int out_size, void* d_ws, size_t ws_size,
                              hipStream_t stream) {
    const float* x     = (const float*)d_in[0];
    const int*   ei    = (const int*)  d_in[1];
    const float* u     = (const float*)d_in[2];
    const float* W1    = (const float*)d_in[3];
    const float* root1 = (const float*)d_in[4];
    const float* b1    = (const float*)d_in[5];
    const float* W2    = (const float*)d_in[6];
    const float* root2 = (const float*)d_in[7];
    const float* b2    = (const float*)d_in[8];
    float*       out   = (float*)d_out;

    const int* src = ei;
    const int* dst = ei + NE;

    // ws layout (padded bins: brec/rec4 sized NBINS*BCAP)
    char* p = (char*)d_ws;
    int* binCur   = (int*)p;  p += 4 * 512;
    int* deg      = (int*)p;  p += (size_t)4 * NN;
    int* rowstart = (int*)p;  p += (size_t)4 * NN;
    ull* brec     = (ull*)p;  p += (size_t)8 * NBINS * BCAP;
    unsigned* rec4 = (unsigned*)p;  p += (size_t)4 * NBINS * BCAP;
    unsigned short* xbf = (unsigned short*)p;  p += (size_t)2 * NN * 64;
    unsigned short* hbf = (unsigned short*)p;  p += (size_t)2 * NN * 64;
    unsigned* x8  = (unsigned*)p;  p += (size_t)4 * NN * 16;
    unsigned char* h8 = (unsigned char*)p;  p += (size_t)NN * 64;
    unsigned short* Bp1 = (unsigned short*)p;  p += (size_t)2 * 6 * 4 * 64 * 8;
    unsigned short* Bp2 = (unsigned short*)p;  p += (size_t)2 * 6 * 3 * 64 * 8;

    prep_kernel<<<CVT_B + 12, 256, 0, stream>>>(
        x, xbf, x8, W1, root1, Bp1, W2, root2, Bp2, binCur);
    p3_bin_scatter_kernel<<<(NE + 2047) / 2048, 256, 0, stream>>>(src, dst, u, binCur, brec);
    p4_final_kernel<<<NBINS, 256, 0, stream>>>(brec, binCur, deg, rowstart, rec4);

    const int NWB = (NN + 15) / 16;   // one wave (16 nodes) per block
    fused_kernel<1><<<NWB, 64, 0, stream>>>(rowstart, deg, rec4, x8, xbf,
                                            (const s16x8*)Bp1, b1, hbf, h8, nullptr);
    fused_kernel<2><<<NWB, 64, 0, stream>>>(rowstart, deg, rec4, (const unsigned*)h8, hbf,
                                            (const s16x8*)Bp2, b2, nullptr, nullptr, out);
}